// Round 4
// baseline (1166.144 us; speedup 1.0000x reference)
//
#include <hip/hip_runtime.h>

#define NNODES 100000
#define NEDGES 3200000
#define ETOT   (NEDGES + NNODES)
#define NEG_SLOPE 0.2f

#define NPB 64                                   // nodes per bucket (dst >> 6)
#define NBUCKETS ((NNODES + NPB - 1) / NPB)      // 1563

// edge e in [0, NEDGES): src = ei[e], dst = ei[NEDGES+e]
// edge e in [NEDGES, ETOT): self-loop, src = dst = e - NEDGES
__device__ __forceinline__ void edge_sd(int e, const int* __restrict__ ei, int& s, int& d) {
    if (e < NEDGES) { s = ei[e]; d = ei[NEDGES + e]; }
    else            { s = e - NEDGES; d = s; }
}

__device__ __forceinline__ float lrelu(float v) {
    return v > 0.0f ? v : NEG_SLOPE * v;
}

// ---------------- CSR build ----------------

__global__ void hist_kernel(const int* __restrict__ ei, int* __restrict__ cnt) {
    int e = blockIdx.x * blockDim.x + threadIdx.x;
    if (e >= ETOT) return;
    int s, d; edge_sd(e, ei, s, d);
    atomicAdd(&cnt[d], 1);
}

// single-block exclusive scan over 100k ints (1024 threads, ~98 elems each) — proven
__global__ void scan_kernel(const int* __restrict__ cnt, int* __restrict__ row_start) {
    __shared__ int sums[1024];
    const int CH = (NNODES + 1023) / 1024;  // 98
    int t = threadIdx.x;
    int lo = t * CH;
    int hi = lo + CH; if (hi > NNODES) hi = NNODES; if (lo > NNODES) lo = NNODES;
    int s = 0;
    for (int i = lo; i < hi; ++i) s += cnt[i];
    sums[t] = s;
    __syncthreads();
    for (int off = 1; off < 1024; off <<= 1) {
        int u = (t >= off) ? sums[t - off] : 0;
        __syncthreads();
        sums[t] += u;
        __syncthreads();
    }
    int run = sums[t] - s;  // exclusive offset of this thread's chunk
    for (int i = lo; i < hi; ++i) { row_start[i] = run; run += cnt[i]; }
    if (t == 0) row_start[NNODES] = ETOT;
}

// bucket cursor init: bucket b's region starts at row_start[b*NPB] (offsets are free)
__global__ void init_bcur(const int* __restrict__ row_start, int* __restrict__ bcur) {
    int b = blockIdx.x * blockDim.x + threadIdx.x;
    if (b < NBUCKETS) bcur[b] = row_start[b * NPB];
}

// coarse scatter: append packed (local_dst<<17 | src) into the bucket's contiguous
// region. Slots per bucket are handed out sequentially -> each 64B line of `pairs`
// receives 16 temporally-clustered writes -> ~1x write amplification (vs 16x for
// the old fully-random csr_scatter).
__global__ void bucket_scatter(const int* __restrict__ ei, int* __restrict__ bcur,
                               int* __restrict__ pairs) {
    int e = blockIdx.x * blockDim.x + threadIdx.x;
    if (e >= ETOT) return;
    int s, d; edge_sd(e, ei, s, d);
    int b = d >> 6;                         // NPB = 64
    int slot = atomicAdd(&bcur[b], 1);
    pairs[slot] = ((d & 63) << 17) | s;     // src < 2^17 (100000 < 131072)
}

// fine sort: one workgroup per bucket; 64 LDS cursors; reads its pairs window
// coalesced, writes src ids into an ~8KB contiguous csr_src window (L2-resident).
__global__ void fine_sort(const int* __restrict__ row_start, const int* __restrict__ pairs,
                          int* __restrict__ csr_src) {
    __shared__ int cur[NPB];
    int b = blockIdx.x;
    int node0 = b * NPB;
    int t = threadIdx.x;
    if (t < NPB) {
        int n = node0 + t;
        cur[t] = (n < NNODES) ? row_start[n] : 0;
    }
    __syncthreads();
    int endn = node0 + NPB; if (endn > NNODES) endn = NNODES;
    int base = row_start[node0];
    int end  = row_start[endn];
    for (int i = base + t; i < end; i += blockDim.x) {
        int p = pairs[i];
        int local = p >> 17;
        int slot = atomicAdd(&cur[local], 1);
        csr_src[slot] = p & 0x1FFFF;
    }
}

// ---------------- node transforms (proven) ----------------

__global__ void l1_node(const float* __restrict__ x, const float* __restrict__ W1,
                        const float* __restrict__ a_s, const float* __restrict__ a_d,
                        float* __restrict__ h, float* __restrict__ as_, float* __restrict__ ad_) {
    int n = blockIdx.x * blockDim.x + threadIdx.x;
    if (n >= NNODES) return;
    float x0 = x[2 * n], x1 = x[2 * n + 1];
    float s = 0.f, d = 0.f;
#pragma unroll
    for (int f = 0; f < 16; ++f) {
        float hf = x0 * W1[f] + x1 * W1[16 + f];
        h[n * 16 + f] = hf;
        s += hf * a_s[f];
        d += hf * a_d[f];
    }
    as_[n] = s; ad_[n] = d;
}

__global__ void l2_node(const float* __restrict__ g, const float* __restrict__ W2,
                        const float* __restrict__ a_s, const float* __restrict__ a_d,
                        float* __restrict__ h, float* __restrict__ as_, float* __restrict__ ad_) {
    int n = blockIdx.x * blockDim.x + threadIdx.x;
    if (n >= NNODES) return;
    float gi[16];
#pragma unroll
    for (int k = 0; k < 16; ++k) gi[k] = g[n * 16 + k];
    float s = 0.f, d = 0.f;
#pragma unroll 4
    for (int f = 0; f < 64; ++f) {
        float hf = 0.f;
#pragma unroll
        for (int k = 0; k < 16; ++k) hf += gi[k] * W2[k * 64 + f];
        h[n * 64 + f] = hf;
        s += hf * a_s[f];
        d += hf * a_d[f];
    }
    as_[n] = s; ad_[n] = d;
}

// ---------------- gather aggregation (proven; zero cross-lane ops) ----------------

__global__ void agg64(const int* __restrict__ row_start, const int* __restrict__ csr_src,
                      const float* __restrict__ as_, const float* __restrict__ ad_,
                      const float* __restrict__ h, const float* __restrict__ b,
                      float* __restrict__ out) {
    int wave = threadIdx.x >> 6;
    int lane = threadIdx.x & 63;
    int node = blockIdx.x * 4 + wave;
    if (node >= NNODES) return;
    int base = row_start[node], end = row_start[node + 1];
    float adv = ad_[node];
    float acc = 0.f, ss = 0.f;
#pragma unroll 4
    for (int i = base; i < end; ++i) {
        int sj = csr_src[i];
        float wj = expf(lrelu(as_[sj] + adv));
        ss += wj;
        acc += wj * h[(size_t)sj * 64 + lane];
    }
    float v = acc / ss + b[lane];
    out[(size_t)node * 64 + lane] = v > 0.f ? v : 0.f;
}

__global__ void agg16(const int* __restrict__ row_start, const int* __restrict__ csr_src,
                      const float* __restrict__ as_, const float* __restrict__ ad_,
                      const float* __restrict__ h, const float* __restrict__ b,
                      float* __restrict__ out) {
    int t = blockIdx.x * blockDim.x + threadIdx.x;
    int node = t >> 4;
    int f = t & 15;
    if (node >= NNODES) return;
    int base = row_start[node], end = row_start[node + 1];
    float adv = ad_[node];
    float acc = 0.f, ss = 0.f;
#pragma unroll 4
    for (int i = base; i < end; ++i) {
        int sj = csr_src[i];
        float wj = expf(lrelu(as_[sj] + adv));
        ss += wj;
        acc += wj * h[sj * 16 + f];
    }
    float v = acc / ss + b[f];
    out[node * 16 + f] = v > 0.f ? v : 0.f;
}

extern "C" void kernel_launch(void* const* d_in, const int* in_sizes, int n_in,
                              void* d_out, int out_size, void* d_ws, size_t ws_size,
                              hipStream_t stream) {
    const float* x     = (const float*)d_in[0];
    const int*   ei    = (const int*)  d_in[1];
    const float* W1    = (const float*)d_in[2];
    const float* as1w  = (const float*)d_in[3];
    const float* ad1w  = (const float*)d_in[4];
    const float* b1    = (const float*)d_in[5];
    const float* W2    = (const float*)d_in[6];
    const float* as2w  = (const float*)d_in[7];
    const float* ad2w  = (const float*)d_in[8];
    const float* b2    = (const float*)d_in[9];
    float* out = (float*)d_out;

    // ws layout (4-byte elems, ~40.4 MB — same proven footprint):
    //   row_start[N+4] | cnt[N] | csr_src[ETOT] | hbuf[N*64] | asb[N] | adb[N]
    // cnt doubles as bucket_cursor after the scan. pairs (ETOT ints, 13.2MB)
    // aliases hbuf (25.6MB): CSR build completes before l1_node writes hbuf.
    // g (layer-1 output, N*16) lives in d_out; agg64 fully overwrites d_out.
    int* row_start = (int*)d_ws;
    int* cnt       = row_start + (NNODES + 4);
    int* csr_src   = cnt + NNODES;
    float* hbuf    = (float*)(csr_src + ETOT);
    float* asb     = hbuf + (size_t)NNODES * 64;
    float* adb     = asb + NNODES;
    int* pairs     = (int*)hbuf;   // dead once l1_node runs
    float* g       = out;          // N*16 floats, dead before agg64 overwrites d_out

    const int B = 256;
    const int EB = (ETOT + B - 1) / B;
    const int NB = (NNODES + B - 1) / B;

    // ---- CSR build (two-level counting sort; shared by both layers) ----
    hipMemsetAsync(cnt, 0, sizeof(int) * NNODES, stream);
    hist_kernel<<<EB, B, 0, stream>>>(ei, cnt);
    scan_kernel<<<1, 1024, 0, stream>>>(cnt, row_start);
    init_bcur<<<(NBUCKETS + B - 1) / B, B, 0, stream>>>(row_start, cnt);  // cnt -> bucket cursor
    bucket_scatter<<<EB, B, 0, stream>>>(ei, cnt, pairs);
    fine_sort<<<NBUCKETS, B, 0, stream>>>(row_start, pairs, csr_src);

    // ---- Layer 1 ----
    l1_node<<<NB, B, 0, stream>>>(x, W1, as1w, ad1w, hbuf, asb, adb);
    agg16<<<(NNODES * 16 + B - 1) / B, B, 0, stream>>>(row_start, csr_src, asb, adb, hbuf, b1, g);

    // ---- Layer 2 ----
    l2_node<<<NB, B, 0, stream>>>(g, W2, as2w, ad2w, hbuf, asb, adb);
    agg64<<<(NNODES + 3) / 4, B, 0, stream>>>(row_start, csr_src, asb, adb, hbuf, b2, out);
}

// Round 6
// 769.024 us; speedup vs baseline: 1.5164x; 1.5164x over previous
//
#include <hip/hip_runtime.h>

#define NNODES 100000
#define NEDGES 3200000
#define ETOT   (NEDGES + NNODES)
#define NEG_SLOPE 0.2f
#define NPART 8
#define PART_N (NNODES / NPART)   // 12500 dst nodes per partition (exact)

// edge e in [0, NEDGES): src = ei[e], dst = ei[NEDGES+e]
// edge e in [NEDGES, ETOT): self-loop, src = dst = e - NEDGES
__device__ __forceinline__ void edge_sd(int e, const int* __restrict__ ei, int& s, int& d) {
    if (e < NEDGES) { s = ei[e]; d = ei[NEDGES + e]; }
    else            { s = e - NEDGES; d = s; }
}

__device__ __forceinline__ float lrelu(float v) {
    return v > 0.0f ? v : NEG_SLOPE * v;
}

// ---------------- CSR build (round-3 proven skeleton) ----------------

__global__ void hist_kernel(const int* __restrict__ ei, int* __restrict__ cnt) {
    int e = blockIdx.x * blockDim.x + threadIdx.x;
    if (e >= ETOT) return;
    int s, d; edge_sd(e, ei, s, d);
    atomicAdd(&cnt[d], 1);
}

// single-block exclusive scan over 100k ints (1024 threads, ~98 elems each) — proven
__global__ void scan_kernel(const int* __restrict__ cnt, int* __restrict__ row_start) {
    __shared__ int sums[1024];
    const int CH = (NNODES + 1023) / 1024;  // 98
    int t = threadIdx.x;
    int lo = t * CH;
    int hi = lo + CH; if (hi > NNODES) hi = NNODES; if (lo > NNODES) lo = NNODES;
    int s = 0;
    for (int i = lo; i < hi; ++i) s += cnt[i];
    sums[t] = s;
    __syncthreads();
    for (int off = 1; off < 1024; off <<= 1) {
        int u = (t >= off) ? sums[t - off] : 0;
        __syncthreads();
        sums[t] += u;
        __syncthreads();
    }
    int run = sums[t] - s;  // exclusive offset of this thread's chunk
    for (int i = lo; i < hi; ++i) { row_start[i] = run; run += cnt[i]; }
    if (t == 0) row_start[NNODES] = ETOT;
}

__global__ void copy_cursor(const int* __restrict__ row_start, int* __restrict__ cursor) {
    int i = blockIdx.x * blockDim.x + threadIdx.x;
    if (i < NNODES) cursor[i] = row_start[i];
}

// XCD-partitioned scatter (the ONE change vs round 3): 8x blocks; block b reads
// edge range (b>>3) and keeps only dst in partition (b&7). Under round-robin
// block->XCD dispatch, each partition's contiguous 1.65MB csr_src slice is
// written only from one XCD -> lines stay L2-resident, written back once
// (round-3 version: random 4B stores from all XCDs -> 197MB writeback).
// Same atomic-cursor semantics, same set of writes -> correctness unchanged.
__global__ void csr_scatter_part(const int* __restrict__ ei, int* __restrict__ cursor,
                                 int* __restrict__ csr_src) {
    int part = blockIdx.x & (NPART - 1);
    int e = (blockIdx.x >> 3) * blockDim.x + threadIdx.x;
    if (e >= ETOT) return;
    int s, d; edge_sd(e, ei, s, d);
    if (d / PART_N != part) return;
    int slot = atomicAdd(&cursor[d], 1);
    csr_src[slot] = s;
}

// ---------------- node transforms (proven) ----------------

__global__ void l1_node(const float* __restrict__ x, const float* __restrict__ W1,
                        const float* __restrict__ a_s, const float* __restrict__ a_d,
                        float* __restrict__ h, float* __restrict__ as_, float* __restrict__ ad_) {
    int n = blockIdx.x * blockDim.x + threadIdx.x;
    if (n >= NNODES) return;
    float x0 = x[2 * n], x1 = x[2 * n + 1];
    float s = 0.f, d = 0.f;
#pragma unroll
    for (int f = 0; f < 16; ++f) {
        float hf = x0 * W1[f] + x1 * W1[16 + f];
        h[n * 16 + f] = hf;
        s += hf * a_s[f];
        d += hf * a_d[f];
    }
    as_[n] = s; ad_[n] = d;
}

__global__ void l2_node(const float* __restrict__ g, const float* __restrict__ W2,
                        const float* __restrict__ a_s, const float* __restrict__ a_d,
                        float* __restrict__ h, float* __restrict__ as_, float* __restrict__ ad_) {
    int n = blockIdx.x * blockDim.x + threadIdx.x;
    if (n >= NNODES) return;
    float gi[16];
#pragma unroll
    for (int k = 0; k < 16; ++k) gi[k] = g[n * 16 + k];
    float s = 0.f, d = 0.f;
#pragma unroll 4
    for (int f = 0; f < 64; ++f) {
        float hf = 0.f;
#pragma unroll
        for (int k = 0; k < 16; ++k) hf += gi[k] * W2[k * 64 + f];
        h[n * 64 + f] = hf;
        s += hf * a_s[f];
        d += hf * a_d[f];
    }
    as_[n] = s; ad_[n] = d;
}

// ---------------- gather aggregation (proven; zero cross-lane ops) ----------------

__global__ void agg64(const int* __restrict__ row_start, const int* __restrict__ csr_src,
                      const float* __restrict__ as_, const float* __restrict__ ad_,
                      const float* __restrict__ h, const float* __restrict__ b,
                      float* __restrict__ out) {
    int wave = threadIdx.x >> 6;
    int lane = threadIdx.x & 63;
    int node = blockIdx.x * 4 + wave;
    if (node >= NNODES) return;
    int base = row_start[node], end = row_start[node + 1];
    float adv = ad_[node];
    float acc = 0.f, ss = 0.f;
#pragma unroll 4
    for (int i = base; i < end; ++i) {
        int sj = csr_src[i];
        float wj = expf(lrelu(as_[sj] + adv));
        ss += wj;
        acc += wj * h[(size_t)sj * 64 + lane];
    }
    float v = acc / ss + b[lane];
    out[(size_t)node * 64 + lane] = v > 0.f ? v : 0.f;
}

__global__ void agg16(const int* __restrict__ row_start, const int* __restrict__ csr_src,
                      const float* __restrict__ as_, const float* __restrict__ ad_,
                      const float* __restrict__ h, const float* __restrict__ b,
                      float* __restrict__ out) {
    int t = blockIdx.x * blockDim.x + threadIdx.x;
    int node = t >> 4;
    int f = t & 15;
    if (node >= NNODES) return;
    int base = row_start[node], end = row_start[node + 1];
    float adv = ad_[node];
    float acc = 0.f, ss = 0.f;
#pragma unroll 4
    for (int i = base; i < end; ++i) {
        int sj = csr_src[i];
        float wj = expf(lrelu(as_[sj] + adv));
        ss += wj;
        acc += wj * h[sj * 16 + f];
    }
    float v = acc / ss + b[f];
    out[node * 16 + f] = v > 0.f ? v : 0.f;
}

extern "C" void kernel_launch(void* const* d_in, const int* in_sizes, int n_in,
                              void* d_out, int out_size, void* d_ws, size_t ws_size,
                              hipStream_t stream) {
    const float* x     = (const float*)d_in[0];
    const int*   ei    = (const int*)  d_in[1];
    const float* W1    = (const float*)d_in[2];
    const float* as1w  = (const float*)d_in[3];
    const float* ad1w  = (const float*)d_in[4];
    const float* b1    = (const float*)d_in[5];
    const float* W2    = (const float*)d_in[6];
    const float* as2w  = (const float*)d_in[7];
    const float* ad2w  = (const float*)d_in[8];
    const float* b2    = (const float*)d_in[9];
    float* out = (float*)d_out;

    // ws layout (4-byte elems, ~40.4 MB — round-3 proven layout):
    //   row_start[N+4] | cnt[N] | csr_src[ETOT] | hbuf[N*64] | asb[N] | adb[N]
    // hbuf reused: h1 (N*16) layer 1, h2 (N*64) layer 2. asb/adb reused per layer.
    // g (layer-1 output, N*16) lives in d_out; agg64 fully overwrites d_out.
    int* row_start = (int*)d_ws;
    int* cnt       = row_start + (NNODES + 4);   // doubles as cursor after scan
    int* csr_src   = cnt + NNODES;
    float* hbuf    = (float*)(csr_src + ETOT);
    float* asb     = hbuf + (size_t)NNODES * 64;
    float* adb     = asb + NNODES;
    float* g       = out;  // N*16 floats, dead before agg64 overwrites d_out

    const int B = 256;
    const int EB = (ETOT + B - 1) / B;
    const int NB = (NNODES + B - 1) / B;

    // ---- CSR build (shared by both layers) ----
    hipMemsetAsync(cnt, 0, sizeof(int) * NNODES, stream);
    hist_kernel<<<EB, B, 0, stream>>>(ei, cnt);
    scan_kernel<<<1, 1024, 0, stream>>>(cnt, row_start);
    copy_cursor<<<NB, B, 0, stream>>>(row_start, cnt);   // cnt becomes cursor
    csr_scatter_part<<<EB * NPART, B, 0, stream>>>(ei, cnt, csr_src);

    // ---- Layer 1 ----
    l1_node<<<NB, B, 0, stream>>>(x, W1, as1w, ad1w, hbuf, asb, adb);
    agg16<<<(NNODES * 16 + B - 1) / B, B, 0, stream>>>(row_start, csr_src, asb, adb, hbuf, b1, g);

    // ---- Layer 2 ----
    l2_node<<<NB, B, 0, stream>>>(g, W2, as2w, ad2w, hbuf, asb, adb);
    agg64<<<(NNODES + 3) / 4, B, 0, stream>>>(row_start, csr_src, asb, adb, hbuf, b2, out);
}

// Round 7
// 666.968 us; speedup vs baseline: 1.7484x; 1.1530x over previous
//
#include <hip/hip_runtime.h>

#define NNODES 100000
#define NEDGES 3200000
#define ETOT   (NEDGES + NNODES)
#define NEG_SLOPE 0.2f
#define NPART 8
#define PART_N (NNODES / NPART)   // 12500 dst nodes per partition (exact)

// edge e in [0, NEDGES): src = ei[e], dst = ei[NEDGES+e]
// edge e in [NEDGES, ETOT): self-loop, src = dst = e - NEDGES
__device__ __forceinline__ void edge_sd(int e, const int* __restrict__ ei, int& s, int& d) {
    if (e < NEDGES) { s = ei[e]; d = ei[NEDGES + e]; }
    else            { s = e - NEDGES; d = s; }
}

__device__ __forceinline__ float lrelu(float v) {
    return v > 0.0f ? v : NEG_SLOPE * v;
}

// ---------------- CSR build (round-6 proven, verbatim) ----------------

__global__ void hist_kernel(const int* __restrict__ ei, int* __restrict__ cnt) {
    int e = blockIdx.x * blockDim.x + threadIdx.x;
    if (e >= ETOT) return;
    int s, d; edge_sd(e, ei, s, d);
    atomicAdd(&cnt[d], 1);
}

__global__ void scan_kernel(const int* __restrict__ cnt, int* __restrict__ row_start) {
    __shared__ int sums[1024];
    const int CH = (NNODES + 1023) / 1024;  // 98
    int t = threadIdx.x;
    int lo = t * CH;
    int hi = lo + CH; if (hi > NNODES) hi = NNODES; if (lo > NNODES) lo = NNODES;
    int s = 0;
    for (int i = lo; i < hi; ++i) s += cnt[i];
    sums[t] = s;
    __syncthreads();
    for (int off = 1; off < 1024; off <<= 1) {
        int u = (t >= off) ? sums[t - off] : 0;
        __syncthreads();
        sums[t] += u;
        __syncthreads();
    }
    int run = sums[t] - s;
    for (int i = lo; i < hi; ++i) { row_start[i] = run; run += cnt[i]; }
    if (t == 0) row_start[NNODES] = ETOT;
}

__global__ void copy_cursor(const int* __restrict__ row_start, int* __restrict__ cursor) {
    int i = blockIdx.x * blockDim.x + threadIdx.x;
    if (i < NNODES) cursor[i] = row_start[i];
}

__global__ void csr_scatter_part(const int* __restrict__ ei, int* __restrict__ cursor,
                                 int* __restrict__ csr_src) {
    int part = blockIdx.x & (NPART - 1);
    int e = (blockIdx.x >> 3) * blockDim.x + threadIdx.x;
    if (e >= ETOT) return;
    int s, d; edge_sd(e, ei, s, d);
    if (d / PART_N != part) return;
    int slot = atomicAdd(&cursor[d], 1);
    csr_src[slot] = s;
}

// ---------------- attention-vector precompute ----------------
// as1[n] = h1[n].a_src1 = x[n].(W1 @ a_src1)  -> c1s (2-vec); likewise c1d.
// as2[n] = h2[n].a_src2 = g[n].(W2 @ a_src2)  -> c2s (16-vec); likewise c2d.
// cvec layout: [0,1]=c1s  [2,3]=c1d  [4..19]=c2s  [20..35]=c2d
__global__ void prep(const float* __restrict__ W1, const float* __restrict__ as1,
                     const float* __restrict__ ad1, const float* __restrict__ W2,
                     const float* __restrict__ as2, const float* __restrict__ ad2,
                     float* __restrict__ cvec) {
    int t = threadIdx.x;
    if (t < 2) {
        float s = 0.f, d = 0.f;
        for (int f = 0; f < 16; ++f) { s += W1[t * 16 + f] * as1[f]; d += W1[t * 16 + f] * ad1[f]; }
        cvec[t] = s; cvec[2 + t] = d;
    }
    if (t < 16) {
        float s = 0.f, d = 0.f;
        for (int f = 0; f < 64; ++f) { s += W2[t * 64 + f] * as2[f]; d += W2[t * 64 + f] * ad2[f]; }
        cvec[4 + t] = s; cvec[20 + t] = d;
    }
}

__global__ void alpha1(const float* __restrict__ x, const float* __restrict__ cvec,
                       float* __restrict__ as_, float* __restrict__ ad_) {
    int n = blockIdx.x * blockDim.x + threadIdx.x;
    if (n >= NNODES) return;
    float x0 = x[2 * n], x1 = x[2 * n + 1];
    as_[n] = x0 * cvec[0] + x1 * cvec[1];
    ad_[n] = x0 * cvec[2] + x1 * cvec[3];
}

__global__ void alpha2(const float* __restrict__ g, const float* __restrict__ cvec,
                       float* __restrict__ as_, float* __restrict__ ad_) {
    int n = blockIdx.x * blockDim.x + threadIdx.x;
    if (n >= NNODES) return;
    float s = 0.f, d = 0.f;
#pragma unroll
    for (int k = 0; k < 16; ++k) {
        float gv = g[n * 16 + k];
        s += gv * cvec[4 + k];
        d += gv * cvec[20 + k];
    }
    as_[n] = s; ad_[n] = d;
}

// ---------------- layer 1: aggregate x (2 feats), then @W1 in epilogue ----------------
// One wave per node. Lane-parallel edge walk: coalesced csr_src, x gathers hit an
// 800KB L2-resident table. LDS tree reduction; grid is EXACTLY 25000 blocks x 4
// waves = 100000 nodes, so every thread executes the same __syncthreads sequence.
__global__ void agg_l1(const int* __restrict__ row_start, const int* __restrict__ csr_src,
                       const float* __restrict__ as_, const float* __restrict__ ad_,
                       const float* __restrict__ x, const float* __restrict__ W1,
                       const float* __restrict__ b1, float* __restrict__ g) {
    __shared__ float4 red[4][64];
    int wave = threadIdx.x >> 6, lane = threadIdx.x & 63;
    int node = blockIdx.x * 4 + wave;          // always < NNODES (exact grid)
    int base = row_start[node], end = row_start[node + 1];
    float adv = ad_[node];
    float a0 = 0.f, a1 = 0.f, ss = 0.f;
    const float2* x2 = (const float2*)x;
    for (int i = base + lane; i < end; i += 64) {
        int sj = csr_src[i];
        float w = __expf(lrelu(as_[sj] + adv));
        float2 xv = x2[sj];
        ss += w;
        a0 += w * xv.x;
        a1 += w * xv.y;
    }
    red[wave][lane] = make_float4(a0, a1, ss, 0.f);
    __syncthreads();
#pragma unroll
    for (int s = 32; s > 0; s >>= 1) {
        if (lane < s) {
            float4 u = red[wave][lane], v = red[wave][lane + s];
            red[wave][lane] = make_float4(u.x + v.x, u.y + v.y, u.z + v.z, 0.f);
        }
        __syncthreads();
    }
    float4 r = red[wave][0];                   // broadcast read
    if (lane < 16) {
        float v = (r.x * W1[lane] + r.y * W1[16 + lane]) / r.z + b1[lane];
        g[node * 16 + lane] = v > 0.f ? v : 0.f;
    }
}

// ---------------- layer 2: aggregate g (16 feats), then @W2 (16->64) in epilogue ----
// One wave per node; 4 groups of 16 lanes; group walks edges stride-4 (group-uniform
// broadcast loads of csr_src/as_; 64B coalesced gather of g-row). Cross-group reduce
// + GEMM epilogue via LDS. No shuffles. Exact grid -> uniform barriers.
__global__ void agg_l2(const int* __restrict__ row_start, const int* __restrict__ csr_src,
                       const float* __restrict__ as_, const float* __restrict__ ad_,
                       const float* __restrict__ g, const float* __restrict__ W2,
                       const float* __restrict__ b2, float* __restrict__ out) {
    __shared__ float2 red[4][64];
    __shared__ float  red2[4][16];
    int wave = threadIdx.x >> 6, lane = threadIdx.x & 63;
    int grp = lane >> 4, f = lane & 15;
    int node = blockIdx.x * 4 + wave;          // always < NNODES (exact grid)
    int base = row_start[node], end = row_start[node + 1];
    float adv = ad_[node];
    float acc = 0.f, ss = 0.f;
    for (int i = base + grp; i < end; i += 4) {
        int sj = csr_src[i];                   // uniform within group -> broadcast
        float w = __expf(lrelu(as_[sj] + adv));
        ss += w;
        acc += w * g[sj * 16 + f];             // 16 lanes x 4B = one 64B line
    }
    red[wave][lane] = make_float2(acc, ss);
    __syncthreads();
    if (lane < 16) {
        float2 r0 = red[wave][f], r1 = red[wave][f + 16];
        float2 r2 = red[wave][f + 32], r3 = red[wave][f + 48];
        float accT = r0.x + r1.x + r2.x + r3.x;
        float ssT  = r0.y + r1.y + r2.y + r3.y;
        red2[wave][f] = accT / ssT;            // normalized aggregated feature k
    }
    __syncthreads();
    float o = 0.f;
#pragma unroll
    for (int k = 0; k < 16; ++k)
        o += red2[wave][k] * W2[k * 64 + lane];   // LDS broadcast + coalesced W2 column
    o += b2[lane];
    out[(size_t)node * 64 + lane] = o > 0.f ? o : 0.f;
}

extern "C" void kernel_launch(void* const* d_in, const int* in_sizes, int n_in,
                              void* d_out, int out_size, void* d_ws, size_t ws_size,
                              hipStream_t stream) {
    const float* x     = (const float*)d_in[0];
    const int*   ei    = (const int*)  d_in[1];
    const float* W1    = (const float*)d_in[2];
    const float* as1w  = (const float*)d_in[3];
    const float* ad1w  = (const float*)d_in[4];
    const float* b1    = (const float*)d_in[5];
    const float* W2    = (const float*)d_in[6];
    const float* as2w  = (const float*)d_in[7];
    const float* ad2w  = (const float*)d_in[8];
    const float* b2    = (const float*)d_in[9];
    float* out = (float*)d_out;

    // ws layout (4-byte elems, ~21.2 MB — well under the proven 40.4 MB):
    //   row_start[N+4] | cnt[N] | csr_src[ETOT] | g[N*16] | asb[N] | adb[N] | cvec[64]
    // asb/adb reused: layer-1 alphas, then overwritten by alpha2 for layer 2.
    int* row_start = (int*)d_ws;
    int* cnt       = row_start + (NNODES + 4);   // doubles as cursor after scan
    int* csr_src   = cnt + NNODES;
    float* gbuf    = (float*)(csr_src + ETOT);   // N*16
    float* asb     = gbuf + (size_t)NNODES * 16;
    float* adb     = asb + NNODES;
    float* cvec    = adb + NNODES;               // 36 floats used

    const int B = 256;
    const int EB = (ETOT + B - 1) / B;
    const int NB = (NNODES + B - 1) / B;

    // ---- CSR build (shared by both layers; round-6 proven) ----
    hipMemsetAsync(cnt, 0, sizeof(int) * NNODES, stream);
    hist_kernel<<<EB, B, 0, stream>>>(ei, cnt);
    scan_kernel<<<1, 1024, 0, stream>>>(cnt, row_start);
    copy_cursor<<<NB, B, 0, stream>>>(row_start, cnt);
    csr_scatter_part<<<EB * NPART, B, 0, stream>>>(ei, cnt, csr_src);

    // ---- attention precompute ----
    prep<<<1, 64, 0, stream>>>(W1, as1w, ad1w, W2, as2w, ad2w, cvec);

    // ---- Layer 1: alphas from x, aggregate x, W1 in epilogue ----
    alpha1<<<NB, B, 0, stream>>>(x, cvec, asb, adb);
    agg_l1<<<NNODES / 4, B, 0, stream>>>(row_start, csr_src, asb, adb, x, W1, b1, gbuf);

    // ---- Layer 2: alphas from g, aggregate g, W2 in epilogue ----
    alpha2<<<NB, B, 0, stream>>>(gbuf, cvec, asb, adb);
    agg_l2<<<NNODES / 4, B, 0, stream>>>(row_start, csr_src, asb, adb, gbuf, W2, b2, out);
}

// Round 10
// 511.312 us; speedup vs baseline: 2.2807x; 1.3044x over previous
//
#include <hip/hip_runtime.h>

#define NNODES 100000
#define NEDGES 3200000
#define ETOT   (NEDGES + NNODES)
#define NEG_SLOPE 0.2f
#define NPART 8
#define PART_N (NNODES / NPART)   // 12500 dst nodes per partition (exact)

#define SB 512
#define NSB ((NNODES + SB - 1) / SB)   // 196 scan blocks

// edge e in [0, NEDGES): src = ei[e], dst = ei[NEDGES+e]
// edge e in [NEDGES, ETOT): self-loop, src = dst = e - NEDGES
__device__ __forceinline__ void edge_sd(int e, const int* __restrict__ ei, int& s, int& d) {
    if (e < NEDGES) { s = ei[e]; d = ei[NEDGES + e]; }
    else            { s = e - NEDGES; d = s; }
}

__device__ __forceinline__ float lrelu(float v) {
    return v > 0.0f ? v : NEG_SLOPE * v;
}

// ---------------- CSR build ----------------

__global__ void hist_kernel(const int* __restrict__ ei, int* __restrict__ cnt) {
    int e = blockIdx.x * blockDim.x + threadIdx.x;
    if (e >= ETOT) return;
    int s, d; edge_sd(e, ei, s, d);
    atomicAdd(&cnt[d], 1);
}

// 3-phase device-wide exclusive scan (replaces the 160us single-block scan:
// one CU, 0.16% occupancy, serialized global latency — Guideline 1 violation).

// Phase 1: per-block LDS scan of 512 counts; local exclusive prefix + block sum.
__global__ void scan_local(const int* __restrict__ cnt, int* __restrict__ row_start,
                           int* __restrict__ bsum) {
    __shared__ int arr[SB];
    int b = blockIdx.x, t = threadIdx.x;
    int n = b * SB + t;
    int v = (n < NNODES) ? cnt[n] : 0;
    arr[t] = v;
    __syncthreads();
    for (int o = 1; o < SB; o <<= 1) {
        int u = (t >= o) ? arr[t - o] : 0;
        __syncthreads();
        arr[t] += u;
        __syncthreads();
    }
    if (n < NNODES) row_start[n] = arr[t] - v;   // local exclusive prefix
    if (t == SB - 1) bsum[b] = arr[t];           // block total
}

// Phase 2: scan the 196 block sums (single tiny block).
__global__ void scan_bsum(const int* __restrict__ bsum, int* __restrict__ boff) {
    __shared__ int arr[256];
    int t = threadIdx.x;
    int v = (t < NSB) ? bsum[t] : 0;
    arr[t] = v;
    __syncthreads();
    for (int o = 1; o < 256; o <<= 1) {
        int u = (t >= o) ? arr[t - o] : 0;
        __syncthreads();
        arr[t] += u;
        __syncthreads();
    }
    if (t < NSB) boff[t] = arr[t] - v;           // exclusive block offset
}

// Phase 3: add block offsets; write final row_start AND the scatter cursor
// (folds the old copy_cursor kernel away).
__global__ void scan_add(int* __restrict__ row_start, const int* __restrict__ boff,
                         int* __restrict__ cursor) {
    int b = blockIdx.x, t = threadIdx.x;
    int n = b * SB + t;
    if (n < NNODES) {
        int v = row_start[n] + boff[b];
        row_start[n] = v;
        cursor[n] = v;
    }
    if (b == 0 && t == 0) row_start[NNODES] = ETOT;
}

// XCD-partitioned scatter (round-6 proven): 8x blocks; block b reads edge range
// (b>>3), keeps only dst in partition (b&7) -> each partition's contiguous csr_src
// slice is written from one XCD; lines stay L2-resident, written back once.
__global__ void csr_scatter_part(const int* __restrict__ ei, int* __restrict__ cursor,
                                 int* __restrict__ csr_src) {
    int part = blockIdx.x & (NPART - 1);
    int e = (blockIdx.x >> 3) * blockDim.x + threadIdx.x;
    if (e >= ETOT) return;
    int s, d; edge_sd(e, ei, s, d);
    if (d / PART_N != part) return;
    int slot = atomicAdd(&cursor[d], 1);
    csr_src[slot] = s;
}

// ---------------- attention-vector precompute (round-7 proven) ----------------
// cvec layout: [0,1]=c1s  [2,3]=c1d  [4..19]=c2s  [20..35]=c2d
__global__ void prep(const float* __restrict__ W1, const float* __restrict__ as1,
                     const float* __restrict__ ad1, const float* __restrict__ W2,
                     const float* __restrict__ as2, const float* __restrict__ ad2,
                     float* __restrict__ cvec) {
    int t = threadIdx.x;
    if (t < 2) {
        float s = 0.f, d = 0.f;
        for (int f = 0; f < 16; ++f) { s += W1[t * 16 + f] * as1[f]; d += W1[t * 16 + f] * ad1[f]; }
        cvec[t] = s; cvec[2 + t] = d;
    }
    if (t < 16) {
        float s = 0.f, d = 0.f;
        for (int f = 0; f < 64; ++f) { s += W2[t * 64 + f] * as2[f]; d += W2[t * 64 + f] * ad2[f]; }
        cvec[4 + t] = s; cvec[20 + t] = d;
    }
}

__global__ void alpha1(const float* __restrict__ x, const float* __restrict__ cvec,
                       float* __restrict__ as_, float* __restrict__ ad_) {
    int n = blockIdx.x * blockDim.x + threadIdx.x;
    if (n >= NNODES) return;
    float x0 = x[2 * n], x1 = x[2 * n + 1];
    as_[n] = x0 * cvec[0] + x1 * cvec[1];
    ad_[n] = x0 * cvec[2] + x1 * cvec[3];
}

__global__ void alpha2(const float* __restrict__ g, const float* __restrict__ cvec,
                       float* __restrict__ as_, float* __restrict__ ad_) {
    int n = blockIdx.x * blockDim.x + threadIdx.x;
    if (n >= NNODES) return;
    float s = 0.f, d = 0.f;
#pragma unroll
    for (int k = 0; k < 16; ++k) {
        float gv = g[n * 16 + k];
        s += gv * cvec[4 + k];
        d += gv * cvec[20 + k];
    }
    as_[n] = s; ad_[n] = d;
}

// ---------------- layer 1: aggregate x (2 feats), then @W1 in epilogue (proven) ----
__global__ void agg_l1(const int* __restrict__ row_start, const int* __restrict__ csr_src,
                       const float* __restrict__ as_, const float* __restrict__ ad_,
                       const float* __restrict__ x, const float* __restrict__ W1,
                       const float* __restrict__ b1, float* __restrict__ g) {
    __shared__ float4 red[4][64];
    int wave = threadIdx.x >> 6, lane = threadIdx.x & 63;
    int node = blockIdx.x * 4 + wave;          // always < NNODES (exact grid)
    int base = row_start[node], end = row_start[node + 1];
    float adv = ad_[node];
    float a0 = 0.f, a1 = 0.f, ss = 0.f;
    const float2* x2 = (const float2*)x;
    for (int i = base + lane; i < end; i += 64) {
        int sj = csr_src[i];
        float w = __expf(lrelu(as_[sj] + adv));
        float2 xv = x2[sj];
        ss += w;
        a0 += w * xv.x;
        a1 += w * xv.y;
    }
    red[wave][lane] = make_float4(a0, a1, ss, 0.f);
    __syncthreads();
#pragma unroll
    for (int s = 32; s > 0; s >>= 1) {
        if (lane < s) {
            float4 u = red[wave][lane], v = red[wave][lane + s];
            red[wave][lane] = make_float4(u.x + v.x, u.y + v.y, u.z + v.z, 0.f);
        }
        __syncthreads();
    }
    float4 r = red[wave][0];                   // broadcast read
    if (lane < 16) {
        float v = (r.x * W1[lane] + r.y * W1[16 + lane]) / r.z + b1[lane];
        g[node * 16 + lane] = v > 0.f ? v : 0.f;
    }
}

// ---------------- layer 2: aggregate g (16 feats), @W2 in epilogue (proven) --------
__global__ void agg_l2(const int* __restrict__ row_start, const int* __restrict__ csr_src,
                       const float* __restrict__ as_, const float* __restrict__ ad_,
                       const float* __restrict__ g, const float* __restrict__ W2,
                       const float* __restrict__ b2, float* __restrict__ out) {
    __shared__ float2 red[4][64];
    __shared__ float  red2[4][16];
    int wave = threadIdx.x >> 6, lane = threadIdx.x & 63;
    int grp = lane >> 4, f = lane & 15;
    int node = blockIdx.x * 4 + wave;          // always < NNODES (exact grid)
    int base = row_start[node], end = row_start[node + 1];
    float adv = ad_[node];
    float acc = 0.f, ss = 0.f;
    for (int i = base + grp; i < end; i += 4) {
        int sj = csr_src[i];                   // uniform within group -> broadcast
        float w = __expf(lrelu(as_[sj] + adv));
        ss += w;
        acc += w * g[sj * 16 + f];             // 16 lanes x 4B = one 64B line
    }
    red[wave][lane] = make_float2(acc, ss);
    __syncthreads();
    if (lane < 16) {
        float2 r0 = red[wave][f], r1 = red[wave][f + 16];
        float2 r2 = red[wave][f + 32], r3 = red[wave][f + 48];
        float accT = r0.x + r1.x + r2.x + r3.x;
        float ssT  = r0.y + r1.y + r2.y + r3.y;
        red2[wave][f] = accT / ssT;            // normalized aggregated feature k
    }
    __syncthreads();
    float o = 0.f;
#pragma unroll
    for (int k = 0; k < 16; ++k)
        o += red2[wave][k] * W2[k * 64 + lane];   // LDS broadcast + coalesced W2 column
    o += b2[lane];
    out[(size_t)node * 64 + lane] = o > 0.f ? o : 0.f;
}

extern "C" void kernel_launch(void* const* d_in, const int* in_sizes, int n_in,
                              void* d_out, int out_size, void* d_ws, size_t ws_size,
                              hipStream_t stream) {
    const float* x     = (const float*)d_in[0];
    const int*   ei    = (const int*)  d_in[1];
    const float* W1    = (const float*)d_in[2];
    const float* as1w  = (const float*)d_in[3];
    const float* ad1w  = (const float*)d_in[4];
    const float* b1    = (const float*)d_in[5];
    const float* W2    = (const float*)d_in[6];
    const float* as2w  = (const float*)d_in[7];
    const float* ad2w  = (const float*)d_in[8];
    const float* b2    = (const float*)d_in[9];
    float* out = (float*)d_out;

    // ws layout (4-byte elems, ~21.2 MB):
    //   row_start[N+4] | cnt[N] | csr_src[ETOT] | g[N*16] | asb[N] | adb[N] |
    //   cvec[64] | bsum[256] | boff[256]
    int* row_start = (int*)d_ws;
    int* cnt       = row_start + (NNODES + 4);   // doubles as cursor after scan
    int* csr_src   = cnt + NNODES;
    float* gbuf    = (float*)(csr_src + ETOT);   // N*16
    float* asb     = gbuf + (size_t)NNODES * 16;
    float* adb     = asb + NNODES;
    float* cvec    = adb + NNODES;               // 36 floats used
    int* bsum      = (int*)(cvec + 64);
    int* boff      = bsum + 256;

    const int B = 256;
    const int EB = (ETOT + B - 1) / B;
    const int NB = (NNODES + B - 1) / B;

    // ---- CSR build (shared by both layers) ----
    hipMemsetAsync(cnt, 0, sizeof(int) * NNODES, stream);
    hist_kernel<<<EB, B, 0, stream>>>(ei, cnt);
    scan_local<<<NSB, SB, 0, stream>>>(cnt, row_start, bsum);
    scan_bsum<<<1, 256, 0, stream>>>(bsum, boff);
    scan_add<<<NSB, SB, 0, stream>>>(row_start, boff, cnt);   // cnt becomes cursor
    csr_scatter_part<<<EB * NPART, B, 0, stream>>>(ei, cnt, csr_src);

    // ---- attention precompute ----
    prep<<<1, 64, 0, stream>>>(W1, as1w, ad1w, W2, as2w, ad2w, cvec);

    // ---- Layer 1: alphas from x, aggregate x, W1 in epilogue ----
    alpha1<<<NB, B, 0, stream>>>(x, cvec, asb, adb);
    agg_l1<<<NNODES / 4, B, 0, stream>>>(row_start, csr_src, asb, adb, x, W1, b1, gbuf);

    // ---- Layer 2: alphas from g, aggregate g, W2 in epilogue ----
    alpha2<<<NB, B, 0, stream>>>(gbuf, cvec, asb, adb);
    agg_l2<<<NNODES / 4, B, 0, stream>>>(row_start, csr_src, asb, adb, gbuf, W2, b2, out);
}

// Round 11
// 455.991 us; speedup vs baseline: 2.5574x; 1.1213x over previous
//
#include <hip/hip_runtime.h>

#define NNODES 100000
#define NEDGES 3200000
#define ETOT   (NEDGES + NNODES)
#define NEG_SLOPE 0.2f

#define SB 512
#define NSB ((NNODES + SB - 1) / SB)   // 196 scan blocks (per-node scan)

#define NPB 64                               // nodes per bucket (dst >> 6)
#define NBUCK ((NNODES + NPB - 1) / NPB)     // 1563 buckets
#define NCHUNK 256                           // edge chunks
#define CHUNK_E ((ETOT + NCHUNK - 1) / NCHUNK)  // 12891 edges/chunk
#define M2 (NBUCK * NCHUNK)                  // 400128 (chunk-scan length)
#define NSB2 ((M2 + 511) / 512)              // 782

// edge e in [0, NEDGES): src = ei[e], dst = ei[NEDGES+e]
// edge e in [NEDGES, ETOT): self-loop, src = dst = e - NEDGES
__device__ __forceinline__ void edge_sd(int e, const int* __restrict__ ei, int& s, int& d) {
    if (e < NEDGES) { s = ei[e]; d = ei[NEDGES + e]; }
    else            { s = e - NEDGES; d = s; }
}

__device__ __forceinline__ float lrelu(float v) {
    return v > 0.0f ? v : NEG_SLOPE * v;
}

// ---------------- per-node hist + 3-phase scan (proven, verbatim) ----------------

__global__ void hist_kernel(const int* __restrict__ ei, int* __restrict__ cnt) {
    int e = blockIdx.x * blockDim.x + threadIdx.x;
    if (e >= ETOT) return;
    int s, d; edge_sd(e, ei, s, d);
    atomicAdd(&cnt[d], 1);
}

__global__ void scan_local(const int* __restrict__ cnt, int* __restrict__ row_start,
                           int* __restrict__ bsum) {
    __shared__ int arr[SB];
    int b = blockIdx.x, t = threadIdx.x;
    int n = b * SB + t;
    int v = (n < NNODES) ? cnt[n] : 0;
    arr[t] = v;
    __syncthreads();
    for (int o = 1; o < SB; o <<= 1) {
        int u = (t >= o) ? arr[t - o] : 0;
        __syncthreads();
        arr[t] += u;
        __syncthreads();
    }
    if (n < NNODES) row_start[n] = arr[t] - v;
    if (t == SB - 1) bsum[b] = arr[t];
}

__global__ void scan_bsum(const int* __restrict__ bsum, int* __restrict__ boff) {
    __shared__ int arr[256];
    int t = threadIdx.x;
    int v = (t < NSB) ? bsum[t] : 0;
    arr[t] = v;
    __syncthreads();
    for (int o = 1; o < 256; o <<= 1) {
        int u = (t >= o) ? arr[t - o] : 0;
        __syncthreads();
        arr[t] += u;
        __syncthreads();
    }
    if (t < NSB) boff[t] = arr[t] - v;
}

__global__ void scan_add(int* __restrict__ row_start, const int* __restrict__ boff) {
    int b = blockIdx.x, t = threadIdx.x;
    int n = b * SB + t;
    if (n < NNODES) row_start[n] += boff[b];
    if (b == 0 && t == 0) row_start[NNODES] = ETOT;
}

// ---------------- deterministic chunked bucket sort (replaces csr_scatter_part) ----
// Round-10 evidence: cursor-atomic scatter writes 176MB for a 13.2MB payload.
// Fix: make every pairs region block-private and contiguous by construction.

// Per-chunk LDS histogram over 1563 buckets.
__global__ void chunk_hist(const int* __restrict__ ei, int* __restrict__ H) {
    __shared__ int h[NBUCK];
    int c = blockIdx.x;
    for (int i = threadIdx.x; i < NBUCK; i += blockDim.x) h[i] = 0;
    __syncthreads();
    int lo = c * CHUNK_E, hi = lo + CHUNK_E; if (hi > ETOT) hi = ETOT;
    for (int e = lo + threadIdx.x; e < hi; e += blockDim.x) {
        int d = (e < NEDGES) ? ei[NEDGES + e] : (e - NEDGES);
        atomicAdd(&h[d >> 6], 1);
    }
    __syncthreads();
    for (int i = threadIdx.x; i < NBUCK; i += blockDim.x) H[c * NBUCK + i] = h[i];
}

// 3-phase exclusive scan of H in bucket-major order.
// Linear index i = b*NCHUNK + c (NCHUNK=256: b = i>>8, c = i&255); value = H[c*NBUCK+b].
// Result: off[b*NCHUNK + c] = slot base of (chunk c, bucket b) in pairs.
__global__ void cscan_local(const int* __restrict__ H, int* __restrict__ off,
                            int* __restrict__ bsum2) {
    __shared__ int arr[512];
    int blk = blockIdx.x, t = threadIdx.x;
    int i = blk * 512 + t;
    int v = (i < M2) ? H[(i & (NCHUNK - 1)) * NBUCK + (i >> 8)] : 0;
    arr[t] = v;
    __syncthreads();
    for (int o = 1; o < 512; o <<= 1) {
        int u = (t >= o) ? arr[t - o] : 0;
        __syncthreads();
        arr[t] += u;
        __syncthreads();
    }
    if (i < M2) off[i] = arr[t] - v;
    if (t == 511) bsum2[blk] = arr[t];
}

__global__ void cscan_bsum(const int* __restrict__ bsum2, int* __restrict__ boff2) {
    __shared__ int arr[1024];
    int t = threadIdx.x;
    int v = (t < NSB2) ? bsum2[t] : 0;
    arr[t] = v;
    __syncthreads();
    for (int o = 1; o < 1024; o <<= 1) {
        int u = (t >= o) ? arr[t - o] : 0;
        __syncthreads();
        arr[t] += u;
        __syncthreads();
    }
    if (t < NSB2) boff2[t] = arr[t] - v;
}

__global__ void cscan_add(int* __restrict__ off, const int* __restrict__ boff2) {
    int i = blockIdx.x * 512 + threadIdx.x;
    if (i < M2) off[i] += boff2[blockIdx.x];
}

// Chunk c appends (local_dst<<17 | src) into its own deterministic per-bucket
// regions via LDS cursors. Each (chunk,bucket) run is written by exactly one
// block, contiguously -> ~2x write amp instead of 13x.
__global__ void chunk_scatter(const int* __restrict__ ei, const int* __restrict__ off,
                              int* __restrict__ pairs) {
    __shared__ int cur[NBUCK];
    int c = blockIdx.x;
    for (int b = threadIdx.x; b < NBUCK; b += blockDim.x)
        cur[b] = off[b * NCHUNK + c];
    __syncthreads();
    int lo = c * CHUNK_E, hi = lo + CHUNK_E; if (hi > ETOT) hi = ETOT;
    for (int e = lo + threadIdx.x; e < hi; e += blockDim.x) {
        int s, d; edge_sd(e, ei, s, d);
        int slot = atomicAdd(&cur[d >> 6], 1);
        pairs[slot] = ((d & 63) << 17) | s;   // src < 2^17
    }
}

// fine sort (round-4 PROVEN, verbatim): one block per 64-node bucket; 64 LDS
// cursors from row_start; reads pairs window coalesced; writes csr_src into a
// contiguous ~8KB single-block window. row_start[64b] == off[b*NCHUNK] by
// construction, so the windows line up exactly.
__global__ void fine_sort(const int* __restrict__ row_start, const int* __restrict__ pairs,
                          int* __restrict__ csr_src) {
    __shared__ int cur[NPB];
    int b = blockIdx.x;
    int node0 = b * NPB;
    int t = threadIdx.x;
    if (t < NPB) {
        int n = node0 + t;
        cur[t] = (n < NNODES) ? row_start[n] : 0;
    }
    __syncthreads();
    int endn = node0 + NPB; if (endn > NNODES) endn = NNODES;
    int base = row_start[node0];
    int end  = row_start[endn];
    for (int i = base + t; i < end; i += blockDim.x) {
        int p = pairs[i];
        int local = p >> 17;
        int slot = atomicAdd(&cur[local], 1);
        csr_src[slot] = p & 0x1FFFF;
    }
}

// ---------------- attention-vector precompute (proven) ----------------
// cvec layout: [0,1]=c1s  [2,3]=c1d  [4..19]=c2s  [20..35]=c2d
__global__ void prep(const float* __restrict__ W1, const float* __restrict__ as1,
                     const float* __restrict__ ad1, const float* __restrict__ W2,
                     const float* __restrict__ as2, const float* __restrict__ ad2,
                     float* __restrict__ cvec) {
    int t = threadIdx.x;
    if (t < 2) {
        float s = 0.f, d = 0.f;
        for (int f = 0; f < 16; ++f) { s += W1[t * 16 + f] * as1[f]; d += W1[t * 16 + f] * ad1[f]; }
        cvec[t] = s; cvec[2 + t] = d;
    }
    if (t < 16) {
        float s = 0.f, d = 0.f;
        for (int f = 0; f < 64; ++f) { s += W2[t * 64 + f] * as2[f]; d += W2[t * 64 + f] * ad2[f]; }
        cvec[4 + t] = s; cvec[20 + t] = d;
    }
}

__global__ void alpha1(const float* __restrict__ x, const float* __restrict__ cvec,
                       float* __restrict__ as_, float* __restrict__ ad_) {
    int n = blockIdx.x * blockDim.x + threadIdx.x;
    if (n >= NNODES) return;
    float x0 = x[2 * n], x1 = x[2 * n + 1];
    as_[n] = x0 * cvec[0] + x1 * cvec[1];
    ad_[n] = x0 * cvec[2] + x1 * cvec[3];
}

__global__ void alpha2(const float* __restrict__ g, const float* __restrict__ cvec,
                       float* __restrict__ as_, float* __restrict__ ad_) {
    int n = blockIdx.x * blockDim.x + threadIdx.x;
    if (n >= NNODES) return;
    float s = 0.f, d = 0.f;
#pragma unroll
    for (int k = 0; k < 16; ++k) {
        float gv = g[n * 16 + k];
        s += gv * cvec[4 + k];
        d += gv * cvec[20 + k];
    }
    as_[n] = s; ad_[n] = d;
}

// ---------------- layer 1: aggregate x (2 feats), @W1 in epilogue (proven) ----------
__global__ void agg_l1(const int* __restrict__ row_start, const int* __restrict__ csr_src,
                       const float* __restrict__ as_, const float* __restrict__ ad_,
                       const float* __restrict__ x, const float* __restrict__ W1,
                       const float* __restrict__ b1, float* __restrict__ g) {
    __shared__ float4 red[4][64];
    int wave = threadIdx.x >> 6, lane = threadIdx.x & 63;
    int node = blockIdx.x * 4 + wave;          // always < NNODES (exact grid)
    int base = row_start[node], end = row_start[node + 1];
    float adv = ad_[node];
    float a0 = 0.f, a1 = 0.f, ss = 0.f;
    const float2* x2 = (const float2*)x;
    for (int i = base + lane; i < end; i += 64) {
        int sj = csr_src[i];
        float w = __expf(lrelu(as_[sj] + adv));
        float2 xv = x2[sj];
        ss += w;
        a0 += w * xv.x;
        a1 += w * xv.y;
    }
    red[wave][lane] = make_float4(a0, a1, ss, 0.f);
    __syncthreads();
#pragma unroll
    for (int s = 32; s > 0; s >>= 1) {
        if (lane < s) {
            float4 u = red[wave][lane], v = red[wave][lane + s];
            red[wave][lane] = make_float4(u.x + v.x, u.y + v.y, u.z + v.z, 0.f);
        }
        __syncthreads();
    }
    float4 r = red[wave][0];                   // broadcast read
    if (lane < 16) {
        float v = (r.x * W1[lane] + r.y * W1[16 + lane]) / r.z + b1[lane];
        g[node * 16 + lane] = v > 0.f ? v : 0.f;
    }
}

// ---------------- layer 2: aggregate g (16 feats), @W2 in epilogue (proven) --------
__global__ void agg_l2(const int* __restrict__ row_start, const int* __restrict__ csr_src,
                       const float* __restrict__ as_, const float* __restrict__ ad_,
                       const float* __restrict__ g, const float* __restrict__ W2,
                       const float* __restrict__ b2, float* __restrict__ out) {
    __shared__ float2 red[4][64];
    __shared__ float  red2[4][16];
    int wave = threadIdx.x >> 6, lane = threadIdx.x & 63;
    int grp = lane >> 4, f = lane & 15;
    int node = blockIdx.x * 4 + wave;          // always < NNODES (exact grid)
    int base = row_start[node], end = row_start[node + 1];
    float adv = ad_[node];
    float acc = 0.f, ss = 0.f;
    for (int i = base + grp; i < end; i += 4) {
        int sj = csr_src[i];                   // uniform within group -> broadcast
        float w = __expf(lrelu(as_[sj] + adv));
        ss += w;
        acc += w * g[sj * 16 + f];             // 16 lanes x 4B = one 64B line
    }
    red[wave][lane] = make_float2(acc, ss);
    __syncthreads();
    if (lane < 16) {
        float2 r0 = red[wave][f], r1 = red[wave][f + 16];
        float2 r2 = red[wave][f + 32], r3 = red[wave][f + 48];
        float accT = r0.x + r1.x + r2.x + r3.x;
        float ssT  = r0.y + r1.y + r2.y + r3.y;
        red2[wave][f] = accT / ssT;            // normalized aggregated feature k
    }
    __syncthreads();
    float o = 0.f;
#pragma unroll
    for (int k = 0; k < 16; ++k)
        o += red2[wave][k] * W2[k * 64 + lane];   // LDS broadcast + coalesced W2 column
    o += b2[lane];
    out[(size_t)node * 64 + lane] = o > 0.f ? o : 0.f;
}

extern "C" void kernel_launch(void* const* d_in, const int* in_sizes, int n_in,
                              void* d_out, int out_size, void* d_ws, size_t ws_size,
                              hipStream_t stream) {
    const float* x     = (const float*)d_in[0];
    const int*   ei    = (const int*)  d_in[1];
    const float* W1    = (const float*)d_in[2];
    const float* as1w  = (const float*)d_in[3];
    const float* ad1w  = (const float*)d_in[4];
    const float* b1    = (const float*)d_in[5];
    const float* W2    = (const float*)d_in[6];
    const float* as2w  = (const float*)d_in[7];
    const float* ad2w  = (const float*)d_in[8];
    const float* b2    = (const float*)d_in[9];
    float* out = (float*)d_out;

    // ws layout (4-byte elems, ~37.6 MB; 40.4 MB proven available in round 1):
    //   row_start[N+4] | cnt[N] | csr_src[ETOT] | g[N*16] | asb[N] | adb[N] |
    //   cvec[64] | bsum[256] | boff[256] | pairs[ETOT] | H[M2] | off[M2] |
    //   bsum2[1024] | boff2[1024]
    int* row_start = (int*)d_ws;
    int* cnt       = row_start + (NNODES + 4);
    int* csr_src   = cnt + NNODES;
    float* gbuf    = (float*)(csr_src + ETOT);   // N*16
    float* asb     = gbuf + (size_t)NNODES * 16;
    float* adb     = asb + NNODES;
    float* cvec    = adb + NNODES;               // 36 floats used
    int* bsum      = (int*)(cvec + 64);
    int* boff      = bsum + 256;
    int* pairs     = boff + 256;                 // ETOT
    int* H         = pairs + ETOT;               // M2
    int* off       = H + M2;                     // M2
    int* bsum2     = off + M2;                   // 1024
    int* boff2     = bsum2 + 1024;               // 1024

    const int B = 256;
    const int EB = (ETOT + B - 1) / B;
    const int NB = (NNODES + B - 1) / B;

    // ---- per-node row_start (proven hist + 3-phase scan) ----
    hipMemsetAsync(cnt, 0, sizeof(int) * NNODES, stream);
    hist_kernel<<<EB, B, 0, stream>>>(ei, cnt);
    scan_local<<<NSB, SB, 0, stream>>>(cnt, row_start, bsum);
    scan_bsum<<<1, 256, 0, stream>>>(bsum, boff);
    scan_add<<<NSB, SB, 0, stream>>>(row_start, boff);

    // ---- deterministic chunked bucket sort (replaces cursor-atomic scatter) ----
    chunk_hist<<<NCHUNK, B, 0, stream>>>(ei, H);
    cscan_local<<<NSB2, 512, 0, stream>>>(H, off, bsum2);
    cscan_bsum<<<1, 1024, 0, stream>>>(bsum2, boff2);
    cscan_add<<<NSB2, 512, 0, stream>>>(off, boff2);
    chunk_scatter<<<NCHUNK, B, 0, stream>>>(ei, off, pairs);
    fine_sort<<<NBUCK, B, 0, stream>>>(row_start, pairs, csr_src);

    // ---- attention precompute ----
    prep<<<1, 64, 0, stream>>>(W1, as1w, ad1w, W2, as2w, ad2w, cvec);

    // ---- Layer 1: alphas from x, aggregate x, W1 in epilogue ----
    alpha1<<<NB, B, 0, stream>>>(x, cvec, asb, adb);
    agg_l1<<<NNODES / 4, B, 0, stream>>>(row_start, csr_src, asb, adb, x, W1, b1, gbuf);

    // ---- Layer 2: alphas from g, aggregate g, W2 in epilogue ----
    alpha2<<<NB, B, 0, stream>>>(gbuf, cvec, asb, adb);
    agg_l2<<<NNODES / 4, B, 0, stream>>>(row_start, csr_src, asb, adb, gbuf, W2, b2, out);
}

// Round 13
// 325.198 us; speedup vs baseline: 3.5859x; 1.4022x over previous
//
#include <hip/hip_runtime.h>

#define NNODES 100000
#define NEDGES 3200000
#define ETOT   (NEDGES + NNODES)
#define NEG_SLOPE 0.2f

#define NPB 64                               // nodes per bucket (dst >> 6)
#define NBUCK ((NNODES + NPB - 1) / NPB)     // 1563 buckets
#define NCHUNK 256                           // edge chunks
#define CHUNK_E ((ETOT + NCHUNK - 1) / NCHUNK)  // 12891 edges/chunk
#define M2 (NBUCK * NCHUNK)                  // 400128 (chunk-scan length)
#define NSB2 ((M2 + 511) / 512)              // 782

// edge e in [0, NEDGES): src = ei[e], dst = ei[NEDGES+e]
// edge e in [NEDGES, ETOT): self-loop, src = dst = e - NEDGES
__device__ __forceinline__ void edge_sd(int e, const int* __restrict__ ei, int& s, int& d) {
    if (e < NEDGES) { s = ei[e]; d = ei[NEDGES + e]; }
    else            { s = e - NEDGES; d = s; }
}

__device__ __forceinline__ float lrelu(float v) {
    return v > 0.0f ? v : NEG_SLOPE * v;
}

// ---------------- deterministic chunked bucket sort (round-11 proven) ----------------
// No random global atomics anywhere in the build: per-node counts now come from
// the bucket's own pairs window (round-11 evidence: hist_kernel's 3.3M random
// global atomics wrote 100MB of HBM for a 400KB array).

// Per-chunk LDS histogram over 1563 buckets.
__global__ void chunk_hist(const int* __restrict__ ei, int* __restrict__ H) {
    __shared__ int h[NBUCK];
    int c = blockIdx.x;
    for (int i = threadIdx.x; i < NBUCK; i += blockDim.x) h[i] = 0;
    __syncthreads();
    int lo = c * CHUNK_E, hi = lo + CHUNK_E; if (hi > ETOT) hi = ETOT;
    for (int e = lo + threadIdx.x; e < hi; e += blockDim.x) {
        int d = (e < NEDGES) ? ei[NEDGES + e] : (e - NEDGES);
        atomicAdd(&h[d >> 6], 1);
    }
    __syncthreads();
    for (int i = threadIdx.x; i < NBUCK; i += blockDim.x) H[c * NBUCK + i] = h[i];
}

// 3-phase exclusive scan of H in bucket-major order (round-11 proven).
// Linear index i = b*NCHUNK + c (NCHUNK=256: b = i>>8, c = i&255); value = H[c*NBUCK+b].
// Result: off[b*NCHUNK + c] = slot base of (chunk c, bucket b) in pairs.
__global__ void cscan_local(const int* __restrict__ H, int* __restrict__ off,
                            int* __restrict__ bsum2) {
    __shared__ int arr[512];
    int blk = blockIdx.x, t = threadIdx.x;
    int i = blk * 512 + t;
    int v = (i < M2) ? H[(i & (NCHUNK - 1)) * NBUCK + (i >> 8)] : 0;
    arr[t] = v;
    __syncthreads();
    for (int o = 1; o < 512; o <<= 1) {
        int u = (t >= o) ? arr[t - o] : 0;
        __syncthreads();
        arr[t] += u;
        __syncthreads();
    }
    if (i < M2) off[i] = arr[t] - v;
    if (t == 511) bsum2[blk] = arr[t];
}

__global__ void cscan_bsum(const int* __restrict__ bsum2, int* __restrict__ boff2) {
    __shared__ int arr[1024];
    int t = threadIdx.x;
    int v = (t < NSB2) ? bsum2[t] : 0;
    arr[t] = v;
    __syncthreads();
    for (int o = 1; o < 1024; o <<= 1) {
        int u = (t >= o) ? arr[t - o] : 0;
        __syncthreads();
        arr[t] += u;
        __syncthreads();
    }
    if (t < NSB2) boff2[t] = arr[t] - v;
}

__global__ void cscan_add(int* __restrict__ off, const int* __restrict__ boff2) {
    int i = blockIdx.x * 512 + threadIdx.x;
    if (i < M2) off[i] += boff2[blockIdx.x];
}

// Chunk c appends (local_dst<<17 | src) into its own deterministic per-bucket
// regions via LDS cursors. Block-private contiguous writes (round-11 proven).
__global__ void chunk_scatter(const int* __restrict__ ei, const int* __restrict__ off,
                              int* __restrict__ pairs) {
    __shared__ int cur[NBUCK];
    int c = blockIdx.x;
    for (int b = threadIdx.x; b < NBUCK; b += blockDim.x)
        cur[b] = off[b * NCHUNK + c];
    __syncthreads();
    int lo = c * CHUNK_E, hi = lo + CHUNK_E; if (hi > ETOT) hi = ETOT;
    for (int e = lo + threadIdx.x; e < hi; e += blockDim.x) {
        int s, d; edge_sd(e, ei, s, d);
        int slot = atomicAdd(&cur[d >> 6], 1);
        pairs[slot] = ((d & 63) << 17) | s;   // src < 2^17
    }
}

// fine_sort2 (round-11 fine_sort + in-LDS per-node count/scan): one block per
// 64-node bucket. Counts the 64 local dsts from its pairs window (LDS atomics),
// scans them (Hillis-Steele, 64 wide), writes row_start for its nodes, then
// scatters src ids into the contiguous csr_src window. Replaces hist_kernel +
// the 3-phase per-node scan entirely.
__global__ void fine_sort2(const int* __restrict__ off, const int* __restrict__ pairs,
                           int* __restrict__ row_start, int* __restrict__ csr_src) {
    __shared__ int arr[NPB];
    __shared__ int cur[NPB];
    int b = blockIdx.x;
    int t = threadIdx.x;
    int base = off[b * NCHUNK];
    int bend = (b == NBUCK - 1) ? ETOT : off[(b + 1) * NCHUNK];
    if (t < NPB) arr[t] = 0;
    __syncthreads();
    for (int i = base + t; i < bend; i += blockDim.x)
        atomicAdd(&arr[pairs[i] >> 17], 1);
    __syncthreads();
    int v = (t < NPB) ? arr[t] : 0;
    __syncthreads();
    for (int o = 1; o < NPB; o <<= 1) {           // inclusive scan over 64 counts
        int u = (t < NPB && t >= o) ? arr[t - o] : 0;
        __syncthreads();
        if (t < NPB) arr[t] += u;
        __syncthreads();
    }
    if (t < NPB) {
        int node = b * NPB + t;
        int start = base + arr[t] - v;            // exclusive prefix
        cur[t] = start;
        if (node < NNODES) row_start[node] = start;
    }
    if (b == NBUCK - 1 && t == 0) row_start[NNODES] = ETOT;
    __syncthreads();
    for (int i = base + t; i < bend; i += blockDim.x) {
        int p = pairs[i];
        int slot = atomicAdd(&cur[p >> 17], 1);
        csr_src[slot] = p & 0x1FFFF;
    }
}

// ---------------- attention-vector precompute (proven) ----------------
// cvec layout: [0,1]=c1s  [2,3]=c1d  [4..19]=c2s  [20..35]=c2d
__global__ void prep(const float* __restrict__ W1, const float* __restrict__ as1,
                     const float* __restrict__ ad1, const float* __restrict__ W2,
                     const float* __restrict__ as2, const float* __restrict__ ad2,
                     float* __restrict__ cvec) {
    int t = threadIdx.x;
    if (t < 2) {
        float s = 0.f, d = 0.f;
        for (int f = 0; f < 16; ++f) { s += W1[t * 16 + f] * as1[f]; d += W1[t * 16 + f] * ad1[f]; }
        cvec[t] = s; cvec[2 + t] = d;
    }
    if (t < 16) {
        float s = 0.f, d = 0.f;
        for (int f = 0; f < 64; ++f) { s += W2[t * 64 + f] * as2[f]; d += W2[t * 64 + f] * ad2[f]; }
        cvec[4 + t] = s; cvec[20 + t] = d;
    }
}

__global__ void alpha1(const float* __restrict__ x, const float* __restrict__ cvec,
                       float* __restrict__ as_, float* __restrict__ ad_) {
    int n = blockIdx.x * blockDim.x + threadIdx.x;
    if (n >= NNODES) return;
    float x0 = x[2 * n], x1 = x[2 * n + 1];
    as_[n] = x0 * cvec[0] + x1 * cvec[1];
    ad_[n] = x0 * cvec[2] + x1 * cvec[3];
}

__global__ void alpha2(const float* __restrict__ g, const float* __restrict__ cvec,
                       float* __restrict__ as_, float* __restrict__ ad_) {
    int n = blockIdx.x * blockDim.x + threadIdx.x;
    if (n >= NNODES) return;
    float s = 0.f, d = 0.f;
#pragma unroll
    for (int k = 0; k < 16; ++k) {
        float gv = g[n * 16 + k];
        s += gv * cvec[4 + k];
        d += gv * cvec[20 + k];
    }
    as_[n] = s; ad_[n] = d;
}

// ---------------- layer 1: aggregate x (2 feats), @W1 in epilogue (proven) ----------
__global__ void agg_l1(const int* __restrict__ row_start, const int* __restrict__ csr_src,
                       const float* __restrict__ as_, const float* __restrict__ ad_,
                       const float* __restrict__ x, const float* __restrict__ W1,
                       const float* __restrict__ b1, float* __restrict__ g) {
    __shared__ float4 red[4][64];
    int wave = threadIdx.x >> 6, lane = threadIdx.x & 63;
    int node = blockIdx.x * 4 + wave;          // always < NNODES (exact grid)
    int base = row_start[node], end = row_start[node + 1];
    float adv = ad_[node];
    float a0 = 0.f, a1 = 0.f, ss = 0.f;
    const float2* x2 = (const float2*)x;
    for (int i = base + lane; i < end; i += 64) {
        int sj = csr_src[i];
        float w = __expf(lrelu(as_[sj] + adv));
        float2 xv = x2[sj];
        ss += w;
        a0 += w * xv.x;
        a1 += w * xv.y;
    }
    red[wave][lane] = make_float4(a0, a1, ss, 0.f);
    __syncthreads();
#pragma unroll
    for (int s = 32; s > 0; s >>= 1) {
        if (lane < s) {
            float4 u = red[wave][lane], v = red[wave][lane + s];
            red[wave][lane] = make_float4(u.x + v.x, u.y + v.y, u.z + v.z, 0.f);
        }
        __syncthreads();
    }
    float4 r = red[wave][0];                   // broadcast read
    if (lane < 16) {
        float v = (r.x * W1[lane] + r.y * W1[16 + lane]) / r.z + b1[lane];
        g[node * 16 + lane] = v > 0.f ? v : 0.f;
    }
}

// ---------------- layer 2: aggregate g (16 feats), @W2 in epilogue (proven) --------
__global__ void agg_l2(const int* __restrict__ row_start, const int* __restrict__ csr_src,
                       const float* __restrict__ as_, const float* __restrict__ ad_,
                       const float* __restrict__ g, const float* __restrict__ W2,
                       const float* __restrict__ b2, float* __restrict__ out) {
    __shared__ float2 red[4][64];
    __shared__ float  red2[4][16];
    int wave = threadIdx.x >> 6, lane = threadIdx.x & 63;
    int grp = lane >> 4, f = lane & 15;
    int node = blockIdx.x * 4 + wave;          // always < NNODES (exact grid)
    int base = row_start[node], end = row_start[node + 1];
    float adv = ad_[node];
    float acc = 0.f, ss = 0.f;
    for (int i = base + grp; i < end; i += 4) {
        int sj = csr_src[i];                   // uniform within group -> broadcast
        float w = __expf(lrelu(as_[sj] + adv));
        ss += w;
        acc += w * g[sj * 16 + f];             // 16 lanes x 4B = one 64B line
    }
    red[wave][lane] = make_float2(acc, ss);
    __syncthreads();
    if (lane < 16) {
        float2 r0 = red[wave][f], r1 = red[wave][f + 16];
        float2 r2 = red[wave][f + 32], r3 = red[wave][f + 48];
        float accT = r0.x + r1.x + r2.x + r3.x;
        float ssT  = r0.y + r1.y + r2.y + r3.y;
        red2[wave][f] = accT / ssT;            // normalized aggregated feature k
    }
    __syncthreads();
    float o = 0.f;
#pragma unroll
    for (int k = 0; k < 16; ++k)
        o += red2[wave][k] * W2[k * 64 + lane];   // LDS broadcast + coalesced W2 column
    o += b2[lane];
    out[(size_t)node * 64 + lane] = o > 0.f ? o : 0.f;
}

extern "C" void kernel_launch(void* const* d_in, const int* in_sizes, int n_in,
                              void* d_out, int out_size, void* d_ws, size_t ws_size,
                              hipStream_t stream) {
    const float* x     = (const float*)d_in[0];
    const int*   ei    = (const int*)  d_in[1];
    const float* W1    = (const float*)d_in[2];
    const float* as1w  = (const float*)d_in[3];
    const float* ad1w  = (const float*)d_in[4];
    const float* b1    = (const float*)d_in[5];
    const float* W2    = (const float*)d_in[6];
    const float* as2w  = (const float*)d_in[7];
    const float* ad2w  = (const float*)d_in[8];
    const float* b2    = (const float*)d_in[9];
    float* out = (float*)d_out;

    // ws layout (4-byte elems, ~36 MB; 40.4 MB proven available):
    //   row_start[N+4] | csr_src[ETOT] | g[N*16] | asb[N] | adb[N] | cvec[64] |
    //   pairs[ETOT] | H[M2] | off[M2] | bsum2[1024] | boff2[1024]
    int* row_start = (int*)d_ws;
    int* csr_src   = row_start + (NNODES + 4);
    float* gbuf    = (float*)(csr_src + ETOT);   // N*16
    float* asb     = gbuf + (size_t)NNODES * 16;
    float* adb     = asb + NNODES;
    float* cvec    = adb + NNODES;               // 36 floats used
    int* pairs     = (int*)(cvec + 64);          // ETOT
    int* H         = pairs + ETOT;               // M2
    int* off       = H + M2;                     // M2
    int* bsum2     = off + M2;                   // 1024
    int* boff2     = bsum2 + 1024;               // 1024

    const int B = 256;
    const int NB = (NNODES + B - 1) / B;

    // ---- CSR build: deterministic chunked bucket sort (no random global atomics,
    //      no separate histogram — row_start computed inside fine_sort2) ----
    chunk_hist<<<NCHUNK, B, 0, stream>>>(ei, H);
    cscan_local<<<NSB2, 512, 0, stream>>>(H, off, bsum2);
    cscan_bsum<<<1, 1024, 0, stream>>>(bsum2, boff2);
    cscan_add<<<NSB2, 512, 0, stream>>>(off, boff2);
    chunk_scatter<<<NCHUNK, B, 0, stream>>>(ei, off, pairs);
    fine_sort2<<<NBUCK, B, 0, stream>>>(off, pairs, row_start, csr_src);

    // ---- attention precompute ----
    prep<<<1, 64, 0, stream>>>(W1, as1w, ad1w, W2, as2w, ad2w, cvec);

    // ---- Layer 1: alphas from x, aggregate x, W1 in epilogue ----
    alpha1<<<NB, B, 0, stream>>>(x, cvec, asb, adb);
    agg_l1<<<NNODES / 4, B, 0, stream>>>(row_start, csr_src, asb, adb, x, W1, b1, gbuf);

    // ---- Layer 2: alphas from g, aggregate g, W2 in epilogue ----
    alpha2<<<NB, B, 0, stream>>>(gbuf, cvec, asb, adb);
    agg_l2<<<NNODES / 4, B, 0, stream>>>(row_start, csr_src, asb, adb, gbuf, W2, b2, out);
}

// Round 16
// 312.955 us; speedup vs baseline: 3.7262x; 1.0391x over previous
//
#include <hip/hip_runtime.h>

#define NNODES 100000
#define NEDGES 3200000
#define ETOT   (NEDGES + NNODES)
#define NEG_SLOPE 0.2f

#define NPB 64                               // nodes per bucket (dst >> 6)
#define NBUCK ((NNODES + NPB - 1) / NPB)     // 1563 buckets
#define NCHUNK 256                           // edge chunks
#define CHUNK_E ((ETOT + NCHUNK - 1) / NCHUNK)  // 12891 edges/chunk
#define M2 (NBUCK * NCHUNK)                  // 400128 (chunk-scan length)
#define NSB2 ((M2 + 511) / 512)              // 782

// bf16 storage via raw ushort — no hip_fp16.h / hip_bf16.h dependency.
__device__ __forceinline__ unsigned short f2bf(float f) {
    unsigned u = __float_as_uint(f);
    u += 0x7FFFu + ((u >> 16) & 1u);         // round-to-nearest-even
    return (unsigned short)(u >> 16);
}
__device__ __forceinline__ float bf2f(unsigned short h) {
    return __uint_as_float(((unsigned)h) << 16);
}

// edge e in [0, NEDGES): src = ei[e], dst = ei[NEDGES+e]
// edge e in [NEDGES, ETOT): self-loop, src = dst = e - NEDGES
__device__ __forceinline__ void edge_sd(int e, const int* __restrict__ ei, int& s, int& d) {
    if (e < NEDGES) { s = ei[e]; d = ei[NEDGES + e]; }
    else            { s = e - NEDGES; d = s; }
}

__device__ __forceinline__ float lrelu(float v) {
    return v > 0.0f ? v : NEG_SLOPE * v;
}

// ---------------- deterministic chunked bucket sort (round-13 proven, verbatim) ------

__global__ void chunk_hist(const int* __restrict__ ei, int* __restrict__ H) {
    __shared__ int h[NBUCK];
    int c = blockIdx.x;
    for (int i = threadIdx.x; i < NBUCK; i += blockDim.x) h[i] = 0;
    __syncthreads();
    int lo = c * CHUNK_E, hi = lo + CHUNK_E; if (hi > ETOT) hi = ETOT;
    for (int e = lo + threadIdx.x; e < hi; e += blockDim.x) {
        int d = (e < NEDGES) ? ei[NEDGES + e] : (e - NEDGES);
        atomicAdd(&h[d >> 6], 1);
    }
    __syncthreads();
    for (int i = threadIdx.x; i < NBUCK; i += blockDim.x) H[c * NBUCK + i] = h[i];
}

// 3-phase exclusive scan of H in bucket-major order.
// Linear index i = b*NCHUNK + c (NCHUNK=256: b = i>>8, c = i&255); value = H[c*NBUCK+b].
__global__ void cscan_local(const int* __restrict__ H, int* __restrict__ off,
                            int* __restrict__ bsum2) {
    __shared__ int arr[512];
    int blk = blockIdx.x, t = threadIdx.x;
    int i = blk * 512 + t;
    int v = (i < M2) ? H[(i & (NCHUNK - 1)) * NBUCK + (i >> 8)] : 0;
    arr[t] = v;
    __syncthreads();
    for (int o = 1; o < 512; o <<= 1) {
        int u = (t >= o) ? arr[t - o] : 0;
        __syncthreads();
        arr[t] += u;
        __syncthreads();
    }
    if (i < M2) off[i] = arr[t] - v;
    if (t == 511) bsum2[blk] = arr[t];
}

__global__ void cscan_bsum(const int* __restrict__ bsum2, int* __restrict__ boff2) {
    __shared__ int arr[1024];
    int t = threadIdx.x;
    int v = (t < NSB2) ? bsum2[t] : 0;
    arr[t] = v;
    __syncthreads();
    for (int o = 1; o < 1024; o <<= 1) {
        int u = (t >= o) ? arr[t - o] : 0;
        __syncthreads();
        arr[t] += u;
        __syncthreads();
    }
    if (t < NSB2) boff2[t] = arr[t] - v;
}

__global__ void cscan_add(int* __restrict__ off, const int* __restrict__ boff2) {
    int i = blockIdx.x * 512 + threadIdx.x;
    if (i < M2) off[i] += boff2[blockIdx.x];
}

__global__ void chunk_scatter(const int* __restrict__ ei, const int* __restrict__ off,
                              int* __restrict__ pairs) {
    __shared__ int cur[NBUCK];
    int c = blockIdx.x;
    for (int b = threadIdx.x; b < NBUCK; b += blockDim.x)
        cur[b] = off[b * NCHUNK + c];
    __syncthreads();
    int lo = c * CHUNK_E, hi = lo + CHUNK_E; if (hi > ETOT) hi = ETOT;
    for (int e = lo + threadIdx.x; e < hi; e += blockDim.x) {
        int s, d; edge_sd(e, ei, s, d);
        int slot = atomicAdd(&cur[d >> 6], 1);
        pairs[slot] = ((d & 63) << 17) | s;   // src < 2^17
    }
}

__global__ void fine_sort2(const int* __restrict__ off, const int* __restrict__ pairs,
                           int* __restrict__ row_start, int* __restrict__ csr_src) {
    __shared__ int arr[NPB];
    __shared__ int cur[NPB];
    int b = blockIdx.x;
    int t = threadIdx.x;
    int base = off[b * NCHUNK];
    int bend = (b == NBUCK - 1) ? ETOT : off[(b + 1) * NCHUNK];
    if (t < NPB) arr[t] = 0;
    __syncthreads();
    for (int i = base + t; i < bend; i += blockDim.x)
        atomicAdd(&arr[pairs[i] >> 17], 1);
    __syncthreads();
    int v = (t < NPB) ? arr[t] : 0;
    __syncthreads();
    for (int o = 1; o < NPB; o <<= 1) {           // inclusive scan over 64 counts
        int u = (t < NPB && t >= o) ? arr[t - o] : 0;
        __syncthreads();
        if (t < NPB) arr[t] += u;
        __syncthreads();
    }
    if (t < NPB) {
        int node = b * NPB + t;
        int start = base + arr[t] - v;            // exclusive prefix
        cur[t] = start;
        if (node < NNODES) row_start[node] = start;
    }
    if (b == NBUCK - 1 && t == 0) row_start[NNODES] = ETOT;
    __syncthreads();
    for (int i = base + t; i < bend; i += blockDim.x) {
        int p = pairs[i];
        int slot = atomicAdd(&cur[p >> 17], 1);
        csr_src[slot] = p & 0x1FFFF;
    }
}

// ---------------- attention-vector precompute (proven) ----------------
// cvec layout: [0,1]=c1s  [2,3]=c1d  [4..19]=c2s  [20..35]=c2d
__global__ void prep(const float* __restrict__ W1, const float* __restrict__ as1,
                     const float* __restrict__ ad1, const float* __restrict__ W2,
                     const float* __restrict__ as2, const float* __restrict__ ad2,
                     float* __restrict__ cvec) {
    int t = threadIdx.x;
    if (t < 2) {
        float s = 0.f, d = 0.f;
        for (int f = 0; f < 16; ++f) { s += W1[t * 16 + f] * as1[f]; d += W1[t * 16 + f] * ad1[f]; }
        cvec[t] = s; cvec[2 + t] = d;
    }
    if (t < 16) {
        float s = 0.f, d = 0.f;
        for (int f = 0; f < 64; ++f) { s += W2[t * 64 + f] * as2[f]; d += W2[t * 64 + f] * ad2[f]; }
        cvec[4 + t] = s; cvec[20 + t] = d;
    }
}

__global__ void alpha1(const float* __restrict__ x, const float* __restrict__ cvec,
                       float* __restrict__ as_, float* __restrict__ ad_) {
    int n = blockIdx.x * blockDim.x + threadIdx.x;
    if (n >= NNODES) return;
    float x0 = x[2 * n], x1 = x[2 * n + 1];
    as_[n] = x0 * cvec[0] + x1 * cvec[1];
    ad_[n] = x0 * cvec[2] + x1 * cvec[3];
}

// alpha2 reads the bf16 g table (half the bytes of fp32).
__global__ void alpha2(const unsigned short* __restrict__ g, const float* __restrict__ cvec,
                       float* __restrict__ as_, float* __restrict__ ad_) {
    int n = blockIdx.x * blockDim.x + threadIdx.x;
    if (n >= NNODES) return;
    float s = 0.f, d = 0.f;
#pragma unroll
    for (int k = 0; k < 16; ++k) {
        float gv = bf2f(g[n * 16 + k]);
        s += gv * cvec[4 + k];
        d += gv * cvec[20 + k];
    }
    as_[n] = s; ad_[n] = d;
}

// ---------------- layer 1: aggregate x (2 feats), @W1 in epilogue ----------
// Change vs round 13: epilogue stores g as bf16 (3.2MB table -> fits per-XCD L2).
__global__ void agg_l1(const int* __restrict__ row_start, const int* __restrict__ csr_src,
                       const float* __restrict__ as_, const float* __restrict__ ad_,
                       const float* __restrict__ x, const float* __restrict__ W1,
                       const float* __restrict__ b1, unsigned short* __restrict__ g) {
    __shared__ float4 red[4][64];
    int wave = threadIdx.x >> 6, lane = threadIdx.x & 63;
    int node = blockIdx.x * 4 + wave;          // always < NNODES (exact grid)
    int base = row_start[node], end = row_start[node + 1];
    float adv = ad_[node];
    float a0 = 0.f, a1 = 0.f, ss = 0.f;
    const float2* x2 = (const float2*)x;
    for (int i = base + lane; i < end; i += 64) {
        int sj = csr_src[i];
        float w = __expf(lrelu(as_[sj] + adv));
        float2 xv = x2[sj];
        ss += w;
        a0 += w * xv.x;
        a1 += w * xv.y;
    }
    red[wave][lane] = make_float4(a0, a1, ss, 0.f);
    __syncthreads();
#pragma unroll
    for (int s = 32; s > 0; s >>= 1) {
        if (lane < s) {
            float4 u = red[wave][lane], v = red[wave][lane + s];
            red[wave][lane] = make_float4(u.x + v.x, u.y + v.y, u.z + v.z, 0.f);
        }
        __syncthreads();
    }
    float4 r = red[wave][0];                   // broadcast read
    if (lane < 16) {
        float v = (r.x * W1[lane] + r.y * W1[16 + lane]) / r.z + b1[lane];
        g[node * 16 + lane] = f2bf(v > 0.f ? v : 0.f);
    }
}

// ---------------- layer 2: aggregate bf16 g (16 feats), @W2 in epilogue --------
// Round-13 evidence: 162MB FETCH from random 64B g-row gathers missing the 4MB
// per-XCD L2 (table was 6.4MB). bf16 table = 3.2MB -> L2-resident; 32B rows.
__global__ void agg_l2(const int* __restrict__ row_start, const int* __restrict__ csr_src,
                       const float* __restrict__ as_, const float* __restrict__ ad_,
                       const unsigned short* __restrict__ g, const float* __restrict__ W2,
                       const float* __restrict__ b2, float* __restrict__ out) {
    __shared__ float2 red[4][64];
    __shared__ float  red2[4][16];
    int wave = threadIdx.x >> 6, lane = threadIdx.x & 63;
    int grp = lane >> 4, f = lane & 15;
    int node = blockIdx.x * 4 + wave;          // always < NNODES (exact grid)
    int base = row_start[node], end = row_start[node + 1];
    float adv = ad_[node];
    float acc = 0.f, ss = 0.f;
    for (int i = base + grp; i < end; i += 4) {
        int sj = csr_src[i];                   // uniform within group -> broadcast
        float w = __expf(lrelu(as_[sj] + adv));
        ss += w;
        acc += w * bf2f(g[sj * 16 + f]);       // 16 lanes x 2B = 32B of one line
    }
    red[wave][lane] = make_float2(acc, ss);
    __syncthreads();
    if (lane < 16) {
        float2 r0 = red[wave][f], r1 = red[wave][f + 16];
        float2 r2 = red[wave][f + 32], r3 = red[wave][f + 48];
        float accT = r0.x + r1.x + r2.x + r3.x;
        float ssT  = r0.y + r1.y + r2.y + r3.y;
        red2[wave][f] = accT / ssT;            // normalized aggregated feature k
    }
    __syncthreads();
    float o = 0.f;
#pragma unroll
    for (int k = 0; k < 16; ++k)
        o += red2[wave][k] * W2[k * 64 + lane];   // LDS broadcast + coalesced W2 column
    o += b2[lane];
    out[(size_t)node * 64 + lane] = o > 0.f ? o : 0.f;
}

extern "C" void kernel_launch(void* const* d_in, const int* in_sizes, int n_in,
                              void* d_out, int out_size, void* d_ws, size_t ws_size,
                              hipStream_t stream) {
    const float* x     = (const float*)d_in[0];
    const int*   ei    = (const int*)  d_in[1];
    const float* W1    = (const float*)d_in[2];
    const float* as1w  = (const float*)d_in[3];
    const float* ad1w  = (const float*)d_in[4];
    const float* b1    = (const float*)d_in[5];
    const float* W2    = (const float*)d_in[6];
    const float* as2w  = (const float*)d_in[7];
    const float* ad2w  = (const float*)d_in[8];
    const float* b2    = (const float*)d_in[9];
    float* out = (float*)d_out;

    // ws layout (4-byte elems, ~36 MB; 40.4 MB proven available):
    //   row_start[N+4] | csr_src[ETOT] | g[N*16 bf16, in former float slot] |
    //   asb[N] | adb[N] | cvec[64] | pairs[ETOT] | H[M2] | off[M2] |
    //   bsum2[1024] | boff2[1024]
    // g region kept at its old (float-sized) footprint so other offsets are
    // unchanged vs the proven round-13 layout; only 3.2MB of it is used now.
    int* row_start = (int*)d_ws;
    int* csr_src   = row_start + (NNODES + 4);
    float* gslot   = (float*)(csr_src + ETOT);   // N*16 floats reserved
    unsigned short* gbuf = (unsigned short*)gslot;  // N*16 bf16 used
    float* asb     = gslot + (size_t)NNODES * 16;
    float* adb     = asb + NNODES;
    float* cvec    = adb + NNODES;               // 36 floats used
    int* pairs     = (int*)(cvec + 64);          // ETOT
    int* H         = pairs + ETOT;               // M2
    int* off       = H + M2;                     // M2
    int* bsum2     = off + M2;                   // 1024
    int* boff2     = bsum2 + 1024;               // 1024

    const int B = 256;
    const int NB = (NNODES + B - 1) / B;

    // ---- CSR build: deterministic chunked bucket sort (round-13 proven) ----
    chunk_hist<<<NCHUNK, B, 0, stream>>>(ei, H);
    cscan_local<<<NSB2, 512, 0, stream>>>(H, off, bsum2);
    cscan_bsum<<<1, 1024, 0, stream>>>(bsum2, boff2);
    cscan_add<<<NSB2, 512, 0, stream>>>(off, boff2);
    chunk_scatter<<<NCHUNK, B, 0, stream>>>(ei, off, pairs);
    fine_sort2<<<NBUCK, B, 0, stream>>>(off, pairs, row_start, csr_src);

    // ---- attention precompute ----
    prep<<<1, 64, 0, stream>>>(W1, as1w, ad1w, W2, as2w, ad2w, cvec);

    // ---- Layer 1: alphas from x, aggregate x, W1 in epilogue (g stored bf16) ----
    alpha1<<<NB, B, 0, stream>>>(x, cvec, asb, adb);
    agg_l1<<<NNODES / 4, B, 0, stream>>>(row_start, csr_src, asb, adb, x, W1, b1, gbuf);

    // ---- Layer 2: alphas from bf16 g, aggregate bf16 g, W2 in epilogue ----
    alpha2<<<NB, B, 0, stream>>>(gbuf, cvec, asb, adb);
    agg_l2<<<NNODES / 4, B, 0, stream>>>(row_start, csr_src, asb, adb, gbuf, W2, b2, out);
}

// Round 18
// 291.829 us; speedup vs baseline: 3.9960x; 1.0724x over previous
//
#include <hip/hip_runtime.h>

#define NNODES 100000
#define NEDGES 3200000
#define ETOT   (NEDGES + NNODES)
#define NEG_SLOPE 0.2f

#define NPB 64                               // nodes per bucket (dst >> 6)
#define NBUCK ((NNODES + NPB - 1) / NPB)     // 1563 buckets
#define NCHUNK 256                           // edge chunks
#define CHUNK_E ((ETOT + NCHUNK - 1) / NCHUNK)  // 12891 edges/chunk
#define M2 (NBUCK * NCHUNK)                  // 400128 (chunk-scan length)
#define NSB2 ((M2 + 511) / 512)              // 782

// bf16 storage via raw ushort — no hip_fp16.h / hip_bf16.h dependency.
__device__ __forceinline__ unsigned short f2bf(float f) {
    unsigned u = __float_as_uint(f);
    u += 0x7FFFu + ((u >> 16) & 1u);         // round-to-nearest-even
    return (unsigned short)(u >> 16);
}
__device__ __forceinline__ float bf2f(unsigned short h) {
    return __uint_as_float(((unsigned)h) << 16);
}

// edge e in [0, NEDGES): src = ei[e], dst = ei[NEDGES+e]
// edge e in [NEDGES, ETOT): self-loop, src = dst = e - NEDGES
__device__ __forceinline__ void edge_sd(int e, const int* __restrict__ ei, int& s, int& d) {
    if (e < NEDGES) { s = ei[e]; d = ei[NEDGES + e]; }
    else            { s = e - NEDGES; d = s; }
}

__device__ __forceinline__ float lrelu(float v) {
    return v > 0.0f ? v : NEG_SLOPE * v;
}

// ---------------- deterministic chunked bucket sort (round-13 proven, verbatim) ------

__global__ void chunk_hist(const int* __restrict__ ei, int* __restrict__ H) {
    __shared__ int h[NBUCK];
    int c = blockIdx.x;
    for (int i = threadIdx.x; i < NBUCK; i += blockDim.x) h[i] = 0;
    __syncthreads();
    int lo = c * CHUNK_E, hi = lo + CHUNK_E; if (hi > ETOT) hi = ETOT;
    for (int e = lo + threadIdx.x; e < hi; e += blockDim.x) {
        int d = (e < NEDGES) ? ei[NEDGES + e] : (e - NEDGES);
        atomicAdd(&h[d >> 6], 1);
    }
    __syncthreads();
    for (int i = threadIdx.x; i < NBUCK; i += blockDim.x) H[c * NBUCK + i] = h[i];
}

// 3-phase exclusive scan of H in bucket-major order.
// Linear index i = b*NCHUNK + c (NCHUNK=256: b = i>>8, c = i&255); value = H[c*NBUCK+b].
__global__ void cscan_local(const int* __restrict__ H, int* __restrict__ off,
                            int* __restrict__ bsum2) {
    __shared__ int arr[512];
    int blk = blockIdx.x, t = threadIdx.x;
    int i = blk * 512 + t;
    int v = (i < M2) ? H[(i & (NCHUNK - 1)) * NBUCK + (i >> 8)] : 0;
    arr[t] = v;
    __syncthreads();
    for (int o = 1; o < 512; o <<= 1) {
        int u = (t >= o) ? arr[t - o] : 0;
        __syncthreads();
        arr[t] += u;
        __syncthreads();
    }
    if (i < M2) off[i] = arr[t] - v;
    if (t == 511) bsum2[blk] = arr[t];
}

__global__ void cscan_bsum(const int* __restrict__ bsum2, int* __restrict__ boff2) {
    __shared__ int arr[1024];
    int t = threadIdx.x;
    int v = (t < NSB2) ? bsum2[t] : 0;
    arr[t] = v;
    __syncthreads();
    for (int o = 1; o < 1024; o <<= 1) {
        int u = (t >= o) ? arr[t - o] : 0;
        __syncthreads();
        arr[t] += u;
        __syncthreads();
    }
    if (t < NSB2) boff2[t] = arr[t] - v;
}

__global__ void cscan_add(int* __restrict__ off, const int* __restrict__ boff2) {
    int i = blockIdx.x * 512 + threadIdx.x;
    if (i < M2) off[i] += boff2[blockIdx.x];
}

__global__ void chunk_scatter(const int* __restrict__ ei, const int* __restrict__ off,
                              int* __restrict__ pairs) {
    __shared__ int cur[NBUCK];
    int c = blockIdx.x;
    for (int b = threadIdx.x; b < NBUCK; b += blockDim.x)
        cur[b] = off[b * NCHUNK + c];
    __syncthreads();
    int lo = c * CHUNK_E, hi = lo + CHUNK_E; if (hi > ETOT) hi = ETOT;
    for (int e = lo + threadIdx.x; e < hi; e += blockDim.x) {
        int s, d; edge_sd(e, ei, s, d);
        int slot = atomicAdd(&cur[d >> 6], 1);
        pairs[slot] = ((d & 63) << 17) | s;   // src < 2^17
    }
}

__global__ void fine_sort2(const int* __restrict__ off, const int* __restrict__ pairs,
                           int* __restrict__ row_start, int* __restrict__ csr_src) {
    __shared__ int arr[NPB];
    __shared__ int cur[NPB];
    int b = blockIdx.x;
    int t = threadIdx.x;
    int base = off[b * NCHUNK];
    int bend = (b == NBUCK - 1) ? ETOT : off[(b + 1) * NCHUNK];
    if (t < NPB) arr[t] = 0;
    __syncthreads();
    for (int i = base + t; i < bend; i += blockDim.x)
        atomicAdd(&arr[pairs[i] >> 17], 1);
    __syncthreads();
    int v = (t < NPB) ? arr[t] : 0;
    __syncthreads();
    for (int o = 1; o < NPB; o <<= 1) {           // inclusive scan over 64 counts
        int u = (t < NPB && t >= o) ? arr[t - o] : 0;
        __syncthreads();
        if (t < NPB) arr[t] += u;
        __syncthreads();
    }
    if (t < NPB) {
        int node = b * NPB + t;
        int start = base + arr[t] - v;            // exclusive prefix
        cur[t] = start;
        if (node < NNODES) row_start[node] = start;
    }
    if (b == NBUCK - 1 && t == 0) row_start[NNODES] = ETOT;
    __syncthreads();
    for (int i = base + t; i < bend; i += blockDim.x) {
        int p = pairs[i];
        int slot = atomicAdd(&cur[p >> 17], 1);
        csr_src[slot] = p & 0x1FFFF;
    }
}

// ---------------- attention-vector precompute (proven) ----------------
// cvec layout: [0,1]=c1s  [2,3]=c1d  [4..19]=c2s  [20..35]=c2d
__global__ void prep(const float* __restrict__ W1, const float* __restrict__ as1,
                     const float* __restrict__ ad1, const float* __restrict__ W2,
                     const float* __restrict__ as2, const float* __restrict__ ad2,
                     float* __restrict__ cvec) {
    int t = threadIdx.x;
    if (t < 2) {
        float s = 0.f, d = 0.f;
        for (int f = 0; f < 16; ++f) { s += W1[t * 16 + f] * as1[f]; d += W1[t * 16 + f] * ad1[f]; }
        cvec[t] = s; cvec[2 + t] = d;
    }
    if (t < 16) {
        float s = 0.f, d = 0.f;
        for (int f = 0; f < 64; ++f) { s += W2[t * 64 + f] * as2[f]; d += W2[t * 64 + f] * ad2[f]; }
        cvec[4 + t] = s; cvec[20 + t] = d;
    }
}

__global__ void alpha1(const float* __restrict__ x, const float* __restrict__ cvec,
                       float* __restrict__ as_, float* __restrict__ ad_) {
    int n = blockIdx.x * blockDim.x + threadIdx.x;
    if (n >= NNODES) return;
    float x0 = x[2 * n], x1 = x[2 * n + 1];
    as_[n] = x0 * cvec[0] + x1 * cvec[1];
    ad_[n] = x0 * cvec[2] + x1 * cvec[3];
}

// alpha2 reads the bf16 g table.
__global__ void alpha2(const unsigned short* __restrict__ g, const float* __restrict__ cvec,
                       float* __restrict__ as_, float* __restrict__ ad_) {
    int n = blockIdx.x * blockDim.x + threadIdx.x;
    if (n >= NNODES) return;
    float s = 0.f, d = 0.f;
#pragma unroll
    for (int k = 0; k < 16; ++k) {
        float gv = bf2f(g[n * 16 + k]);
        s += gv * cvec[4 + k];
        d += gv * cvec[20 + k];
    }
    as_[n] = s; ad_[n] = d;
}

// ---------------- layer 1: aggregate x (2 feats), @W1 in epilogue (proven) ----------
__global__ void agg_l1(const int* __restrict__ row_start, const int* __restrict__ csr_src,
                       const float* __restrict__ as_, const float* __restrict__ ad_,
                       const float* __restrict__ x, const float* __restrict__ W1,
                       const float* __restrict__ b1, unsigned short* __restrict__ g) {
    __shared__ float4 red[4][64];
    int wave = threadIdx.x >> 6, lane = threadIdx.x & 63;
    int node = blockIdx.x * 4 + wave;          // always < NNODES (exact grid)
    int base = row_start[node], end = row_start[node + 1];
    float adv = ad_[node];
    float a0 = 0.f, a1 = 0.f, ss = 0.f;
    const float2* x2 = (const float2*)x;
    for (int i = base + lane; i < end; i += 64) {
        int sj = csr_src[i];
        float w = __expf(lrelu(as_[sj] + adv));
        float2 xv = x2[sj];
        ss += w;
        a0 += w * xv.x;
        a1 += w * xv.y;
    }
    red[wave][lane] = make_float4(a0, a1, ss, 0.f);
    __syncthreads();
#pragma unroll
    for (int s = 32; s > 0; s >>= 1) {
        if (lane < s) {
            float4 u = red[wave][lane], v = red[wave][lane + s];
            red[wave][lane] = make_float4(u.x + v.x, u.y + v.y, u.z + v.z, 0.f);
        }
        __syncthreads();
    }
    float4 r = red[wave][0];                   // broadcast read
    if (lane < 16) {
        float v = (r.x * W1[lane] + r.y * W1[16 + lane]) / r.z + b1[lane];
        g[node * 16 + lane] = f2bf(v > 0.f ? v : 0.f);
    }
}

// ---------------- layer 2: aggregate bf16 g, @W2 in epilogue ------------------------
// Round-16 evidence: FETCH fixed (41MB) but dur only 96us — latency-bound, only 4
// gathers in flight/wave. New geometry: 16 groups x 4 lanes; each lane loads a
// ushort4 (8B) of the 32B row -> 16 rows in flight (4x MLP), exp redundancy 16->4.
__global__ void agg_l2(const int* __restrict__ row_start, const int* __restrict__ csr_src,
                       const float* __restrict__ as_, const float* __restrict__ ad_,
                       const unsigned short* __restrict__ g, const float* __restrict__ W2,
                       const float* __restrict__ b2, float* __restrict__ out) {
    __shared__ float red[4][256];     // lane-major: [wave][lane*4 + j] = acc quad
    __shared__ float ssred[4][16];    // [wave][grp] = ss partial
    __shared__ float red2[4][16];     // normalized aggregated feature
    int wave = threadIdx.x >> 6, lane = threadIdx.x & 63;
    int grp = lane >> 2;              // 0..15: edge group
    int q   = lane & 3;               // 0..3:  feature quad (features q*4..q*4+3)
    int node = blockIdx.x * 4 + wave; // always < NNODES (exact grid)
    int base = row_start[node], end = row_start[node + 1];
    float adv = ad_[node];
    float a0 = 0.f, a1 = 0.f, a2 = 0.f, a3 = 0.f, ss = 0.f;
    for (int i = base + grp; i < end; i += 16) {
        int sj = csr_src[i];                       // uniform within 4-lane group
        float w = __expf(lrelu(as_[sj] + adv));
        ss += w;
        const ushort4* gp = (const ushort4*)(g + sj * 16);  // row 32B-aligned
        ushort4 hv = gp[q];                        // 8B per lane, 32B per group
        a0 += w * bf2f(hv.x);
        a1 += w * bf2f(hv.y);
        a2 += w * bf2f(hv.z);
        a3 += w * bf2f(hv.w);
    }
    red[wave][lane * 4 + 0] = a0;
    red[wave][lane * 4 + 1] = a1;
    red[wave][lane * 4 + 2] = a2;
    red[wave][lane * 4 + 3] = a3;
    if (q == 0) ssred[wave][grp] = ss;
    __syncthreads();
    if (lane < 16) {
        // feature f = lane lives in quad qq at position j; sum over 16 groups
        int qq = lane >> 2, j = lane & 3;
        float a = 0.f, st = 0.f;
#pragma unroll
        for (int gg = 0; gg < 16; ++gg) {
            a  += red[wave][(gg * 4 + qq) * 4 + j];
            st += ssred[wave][gg];
        }
        red2[wave][lane] = a / st;
    }
    __syncthreads();
    float o = 0.f;
#pragma unroll
    for (int k = 0; k < 16; ++k)
        o += red2[wave][k] * W2[k * 64 + lane];   // LDS broadcast + coalesced W2 column
    o += b2[lane];
    out[(size_t)node * 64 + lane] = o > 0.f ? o : 0.f;
}

extern "C" void kernel_launch(void* const* d_in, const int* in_sizes, int n_in,
                              void* d_out, int out_size, void* d_ws, size_t ws_size,
                              hipStream_t stream) {
    const float* x     = (const float*)d_in[0];
    const int*   ei    = (const int*)  d_in[1];
    const float* W1    = (const float*)d_in[2];
    const float* as1w  = (const float*)d_in[3];
    const float* ad1w  = (const float*)d_in[4];
    const float* b1    = (const float*)d_in[5];
    const float* W2    = (const float*)d_in[6];
    const float* as2w  = (const float*)d_in[7];
    const float* ad2w  = (const float*)d_in[8];
    const float* b2    = (const float*)d_in[9];
    float* out = (float*)d_out;

    // ws layout (4-byte elems, ~36 MB; 40.4 MB proven available):
    //   row_start[N+4] | csr_src[ETOT] | g[N*16 bf16, in former float slot] |
    //   asb[N] | adb[N] | cvec[64] | pairs[ETOT] | H[M2] | off[M2] |
    //   bsum2[1024] | boff2[1024]
    int* row_start = (int*)d_ws;
    int* csr_src   = row_start + (NNODES + 4);
    float* gslot   = (float*)(csr_src + ETOT);   // N*16 floats reserved
    unsigned short* gbuf = (unsigned short*)gslot;  // N*16 bf16 used
    float* asb     = gslot + (size_t)NNODES * 16;
    float* adb     = asb + NNODES;
    float* cvec    = adb + NNODES;               // 36 floats used
    int* pairs     = (int*)(cvec + 64);          // ETOT
    int* H         = pairs + ETOT;               // M2
    int* off       = H + M2;                     // M2
    int* bsum2     = off + M2;                   // 1024
    int* boff2     = bsum2 + 1024;               // 1024

    const int B = 256;
    const int NB = (NNODES + B - 1) / B;

    // ---- CSR build: deterministic chunked bucket sort (round-13 proven) ----
    chunk_hist<<<NCHUNK, B, 0, stream>>>(ei, H);
    cscan_local<<<NSB2, 512, 0, stream>>>(H, off, bsum2);
    cscan_bsum<<<1, 1024, 0, stream>>>(bsum2, boff2);
    cscan_add<<<NSB2, 512, 0, stream>>>(off, boff2);
    chunk_scatter<<<NCHUNK, B, 0, stream>>>(ei, off, pairs);
    fine_sort2<<<NBUCK, B, 0, stream>>>(off, pairs, row_start, csr_src);

    // ---- attention precompute ----
    prep<<<1, 64, 0, stream>>>(W1, as1w, ad1w, W2, as2w, ad2w, cvec);

    // ---- Layer 1: alphas from x, aggregate x, W1 in epilogue (g stored bf16) ----
    alpha1<<<NB, B, 0, stream>>>(x, cvec, asb, adb);
    agg_l1<<<NNODES / 4, B, 0, stream>>>(row_start, csr_src, asb, adb, x, W1, b1, gbuf);

    // ---- Layer 2: alphas from bf16 g, aggregate bf16 g, W2 in epilogue ----
    alpha2<<<NB, B, 0, stream>>>(gbuf, cvec, asb, adb);
    agg_l2<<<NNODES / 4, B, 0, stream>>>(row_start, csr_src, asb, adb, gbuf, W2, b2, out);
}

// Round 19
// 282.972 us; speedup vs baseline: 4.1211x; 1.0313x over previous
//
#include <hip/hip_runtime.h>

#define NNODES 100000
#define NEDGES 3200000
#define ETOT   (NEDGES + NNODES)
#define NEG_SLOPE 0.2f

#define NPB 64                               // nodes per bucket (dst >> 6)
#define NBUCK ((NNODES + NPB - 1) / NPB)     // 1563 buckets
#define NCHUNK 256                           // edge chunks
#define CHUNK_E ((ETOT + NCHUNK - 1) / NCHUNK)  // 12891 edges/chunk
#define M2 (NBUCK * NCHUNK)                  // 400128 (chunk-scan length)
#define NSB2 ((M2 + 511) / 512)              // 782

// bf16 storage via raw ushort — no hip_fp16.h / hip_bf16.h dependency.
__device__ __forceinline__ unsigned short f2bf(float f) {
    unsigned u = __float_as_uint(f);
    u += 0x7FFFu + ((u >> 16) & 1u);         // round-to-nearest-even
    return (unsigned short)(u >> 16);
}
__device__ __forceinline__ float bf2f(unsigned short h) {
    return __uint_as_float(((unsigned)h) << 16);
}

// edge e in [0, NEDGES): src = ei[e], dst = ei[NEDGES+e]
// edge e in [NEDGES, ETOT): self-loop, src = dst = e - NEDGES
__device__ __forceinline__ void edge_sd(int e, const int* __restrict__ ei, int& s, int& d) {
    if (e < NEDGES) { s = ei[e]; d = ei[NEDGES + e]; }
    else            { s = e - NEDGES; d = s; }
}

__device__ __forceinline__ float lrelu(float v) {
    return v > 0.0f ? v : NEG_SLOPE * v;
}

// ---------------- deterministic chunked bucket sort ----------------
// Round-18 change: chunk_hist/chunk_scatter launched with 1024 threads (was 256).
// Evidence: OccupancyPercent=9% (256 blocks x 4 waves = 1 block/CU), 50 serial
// edge-loop iterations of LDS-atomic + random write. Kernels are blockDim-strided,
// so this is config-only.

__global__ void chunk_hist(const int* __restrict__ ei, int* __restrict__ H) {
    __shared__ int h[NBUCK];
    int c = blockIdx.x;
    for (int i = threadIdx.x; i < NBUCK; i += blockDim.x) h[i] = 0;
    __syncthreads();
    int lo = c * CHUNK_E, hi = lo + CHUNK_E; if (hi > ETOT) hi = ETOT;
    for (int e = lo + threadIdx.x; e < hi; e += blockDim.x) {
        int d = (e < NEDGES) ? ei[NEDGES + e] : (e - NEDGES);
        atomicAdd(&h[d >> 6], 1);
    }
    __syncthreads();
    for (int i = threadIdx.x; i < NBUCK; i += blockDim.x) H[c * NBUCK + i] = h[i];
}

// 3-phase exclusive scan of H in bucket-major order.
// Linear index i = b*NCHUNK + c (NCHUNK=256: b = i>>8, c = i&255); value = H[c*NBUCK+b].
__global__ void cscan_local(const int* __restrict__ H, int* __restrict__ off,
                            int* __restrict__ bsum2) {
    __shared__ int arr[512];
    int blk = blockIdx.x, t = threadIdx.x;
    int i = blk * 512 + t;
    int v = (i < M2) ? H[(i & (NCHUNK - 1)) * NBUCK + (i >> 8)] : 0;
    arr[t] = v;
    __syncthreads();
    for (int o = 1; o < 512; o <<= 1) {
        int u = (t >= o) ? arr[t - o] : 0;
        __syncthreads();
        arr[t] += u;
        __syncthreads();
    }
    if (i < M2) off[i] = arr[t] - v;
    if (t == 511) bsum2[blk] = arr[t];
}

__global__ void cscan_bsum(const int* __restrict__ bsum2, int* __restrict__ boff2) {
    __shared__ int arr[1024];
    int t = threadIdx.x;
    int v = (t < NSB2) ? bsum2[t] : 0;
    arr[t] = v;
    __syncthreads();
    for (int o = 1; o < 1024; o <<= 1) {
        int u = (t >= o) ? arr[t - o] : 0;
        __syncthreads();
        arr[t] += u;
        __syncthreads();
    }
    if (t < NSB2) boff2[t] = arr[t] - v;
}

__global__ void cscan_add(int* __restrict__ off, const int* __restrict__ boff2) {
    int i = blockIdx.x * 512 + threadIdx.x;
    if (i < M2) off[i] += boff2[blockIdx.x];
}

__global__ void chunk_scatter(const int* __restrict__ ei, const int* __restrict__ off,
                              int* __restrict__ pairs) {
    __shared__ int cur[NBUCK];
    int c = blockIdx.x;
    for (int b = threadIdx.x; b < NBUCK; b += blockDim.x)
        cur[b] = off[b * NCHUNK + c];
    __syncthreads();
    int lo = c * CHUNK_E, hi = lo + CHUNK_E; if (hi > ETOT) hi = ETOT;
    for (int e = lo + threadIdx.x; e < hi; e += blockDim.x) {
        int s, d; edge_sd(e, ei, s, d);
        int slot = atomicAdd(&cur[d >> 6], 1);
        pairs[slot] = ((d & 63) << 17) | s;   // src < 2^17
    }
}

__global__ void fine_sort2(const int* __restrict__ off, const int* __restrict__ pairs,
                           int* __restrict__ row_start, int* __restrict__ csr_src) {
    __shared__ int arr[NPB];
    __shared__ int cur[NPB];
    int b = blockIdx.x;
    int t = threadIdx.x;
    int base = off[b * NCHUNK];
    int bend = (b == NBUCK - 1) ? ETOT : off[(b + 1) * NCHUNK];
    if (t < NPB) arr[t] = 0;
    __syncthreads();
    for (int i = base + t; i < bend; i += blockDim.x)
        atomicAdd(&arr[pairs[i] >> 17], 1);
    __syncthreads();
    int v = (t < NPB) ? arr[t] : 0;
    __syncthreads();
    for (int o = 1; o < NPB; o <<= 1) {           // inclusive scan over 64 counts
        int u = (t < NPB && t >= o) ? arr[t - o] : 0;
        __syncthreads();
        if (t < NPB) arr[t] += u;
        __syncthreads();
    }
    if (t < NPB) {
        int node = b * NPB + t;
        int start = base + arr[t] - v;            // exclusive prefix
        cur[t] = start;
        if (node < NNODES) row_start[node] = start;
    }
    if (b == NBUCK - 1 && t == 0) row_start[NNODES] = ETOT;
    __syncthreads();
    for (int i = base + t; i < bend; i += blockDim.x) {
        int p = pairs[i];
        int slot = atomicAdd(&cur[p >> 17], 1);
        csr_src[slot] = p & 0x1FFFF;
    }
}

// ---------------- attention-vector precompute (proven) ----------------
// cvec layout: [0,1]=c1s  [2,3]=c1d  [4..19]=c2s  [20..35]=c2d
__global__ void prep(const float* __restrict__ W1, const float* __restrict__ as1,
                     const float* __restrict__ ad1, const float* __restrict__ W2,
                     const float* __restrict__ as2, const float* __restrict__ ad2,
                     float* __restrict__ cvec) {
    int t = threadIdx.x;
    if (t < 2) {
        float s = 0.f, d = 0.f;
        for (int f = 0; f < 16; ++f) { s += W1[t * 16 + f] * as1[f]; d += W1[t * 16 + f] * ad1[f]; }
        cvec[t] = s; cvec[2 + t] = d;
    }
    if (t < 16) {
        float s = 0.f, d = 0.f;
        for (int f = 0; f < 64; ++f) { s += W2[t * 64 + f] * as2[f]; d += W2[t * 64 + f] * ad2[f]; }
        cvec[4 + t] = s; cvec[20 + t] = d;
    }
}

__global__ void alpha1(const float* __restrict__ x, const float* __restrict__ cvec,
                       float* __restrict__ as_, float* __restrict__ ad_) {
    int n = blockIdx.x * blockDim.x + threadIdx.x;
    if (n >= NNODES) return;
    float x0 = x[2 * n], x1 = x[2 * n + 1];
    as_[n] = x0 * cvec[0] + x1 * cvec[1];
    ad_[n] = x0 * cvec[2] + x1 * cvec[3];
}

// alpha2 reads the bf16 g table.
__global__ void alpha2(const unsigned short* __restrict__ g, const float* __restrict__ cvec,
                       float* __restrict__ as_, float* __restrict__ ad_) {
    int n = blockIdx.x * blockDim.x + threadIdx.x;
    if (n >= NNODES) return;
    float s = 0.f, d = 0.f;
#pragma unroll
    for (int k = 0; k < 16; ++k) {
        float gv = bf2f(g[n * 16 + k]);
        s += gv * cvec[4 + k];
        d += gv * cvec[20 + k];
    }
    as_[n] = s; ad_[n] = d;
}

// ---------------- layer 1: aggregate x (2 feats), @W1 in epilogue (proven) ----------
__global__ void agg_l1(const int* __restrict__ row_start, const int* __restrict__ csr_src,
                       const float* __restrict__ as_, const float* __restrict__ ad_,
                       const float* __restrict__ x, const float* __restrict__ W1,
                       const float* __restrict__ b1, unsigned short* __restrict__ g) {
    __shared__ float4 red[4][64];
    int wave = threadIdx.x >> 6, lane = threadIdx.x & 63;
    int node = blockIdx.x * 4 + wave;          // always < NNODES (exact grid)
    int base = row_start[node], end = row_start[node + 1];
    float adv = ad_[node];
    float a0 = 0.f, a1 = 0.f, ss = 0.f;
    const float2* x2 = (const float2*)x;
    for (int i = base + lane; i < end; i += 64) {
        int sj = csr_src[i];
        float w = __expf(lrelu(as_[sj] + adv));
        float2 xv = x2[sj];
        ss += w;
        a0 += w * xv.x;
        a1 += w * xv.y;
    }
    red[wave][lane] = make_float4(a0, a1, ss, 0.f);
    __syncthreads();
#pragma unroll
    for (int s = 32; s > 0; s >>= 1) {
        if (lane < s) {
            float4 u = red[wave][lane], v = red[wave][lane + s];
            red[wave][lane] = make_float4(u.x + v.x, u.y + v.y, u.z + v.z, 0.f);
        }
        __syncthreads();
    }
    float4 r = red[wave][0];                   // broadcast read
    if (lane < 16) {
        float v = (r.x * W1[lane] + r.y * W1[16 + lane]) / r.z + b1[lane];
        g[node * 16 + lane] = f2bf(v > 0.f ? v : 0.f);
    }
}

// ---------------- layer 2: aggregate bf16 g, @W2 in epilogue (round-18 proven) ------
// 16 groups x 4 lanes; each lane loads a ushort4 (8B) of the 32B row -> 16 rows
// in flight, exp redundancy 4x.
__global__ void agg_l2(const int* __restrict__ row_start, const int* __restrict__ csr_src,
                       const float* __restrict__ as_, const float* __restrict__ ad_,
                       const unsigned short* __restrict__ g, const float* __restrict__ W2,
                       const float* __restrict__ b2, float* __restrict__ out) {
    __shared__ float red[4][256];     // lane-major: [wave][lane*4 + j] = acc quad
    __shared__ float ssred[4][16];    // [wave][grp] = ss partial
    __shared__ float red2[4][16];     // normalized aggregated feature
    int wave = threadIdx.x >> 6, lane = threadIdx.x & 63;
    int grp = lane >> 2;              // 0..15: edge group
    int q   = lane & 3;               // 0..3:  feature quad (features q*4..q*4+3)
    int node = blockIdx.x * 4 + wave; // always < NNODES (exact grid)
    int base = row_start[node], end = row_start[node + 1];
    float adv = ad_[node];
    float a0 = 0.f, a1 = 0.f, a2 = 0.f, a3 = 0.f, ss = 0.f;
    for (int i = base + grp; i < end; i += 16) {
        int sj = csr_src[i];                       // uniform within 4-lane group
        float w = __expf(lrelu(as_[sj] + adv));
        ss += w;
        const ushort4* gp = (const ushort4*)(g + sj * 16);  // row 32B-aligned
        ushort4 hv = gp[q];                        // 8B per lane, 32B per group
        a0 += w * bf2f(hv.x);
        a1 += w * bf2f(hv.y);
        a2 += w * bf2f(hv.z);
        a3 += w * bf2f(hv.w);
    }
    red[wave][lane * 4 + 0] = a0;
    red[wave][lane * 4 + 1] = a1;
    red[wave][lane * 4 + 2] = a2;
    red[wave][lane * 4 + 3] = a3;
    if (q == 0) ssred[wave][grp] = ss;
    __syncthreads();
    if (lane < 16) {
        // feature f = lane lives in quad qq at position j; sum over 16 groups
        int qq = lane >> 2, j = lane & 3;
        float a = 0.f, st = 0.f;
#pragma unroll
        for (int gg = 0; gg < 16; ++gg) {
            a  += red[wave][(gg * 4 + qq) * 4 + j];
            st += ssred[wave][gg];
        }
        red2[wave][lane] = a / st;
    }
    __syncthreads();
    float o = 0.f;
#pragma unroll
    for (int k = 0; k < 16; ++k)
        o += red2[wave][k] * W2[k * 64 + lane];   // LDS broadcast + coalesced W2 column
    o += b2[lane];
    out[(size_t)node * 64 + lane] = o > 0.f ? o : 0.f;
}

extern "C" void kernel_launch(void* const* d_in, const int* in_sizes, int n_in,
                              void* d_out, int out_size, void* d_ws, size_t ws_size,
                              hipStream_t stream) {
    const float* x     = (const float*)d_in[0];
    const int*   ei    = (const int*)  d_in[1];
    const float* W1    = (const float*)d_in[2];
    const float* as1w  = (const float*)d_in[3];
    const float* ad1w  = (const float*)d_in[4];
    const float* b1    = (const float*)d_in[5];
    const float* W2    = (const float*)d_in[6];
    const float* as2w  = (const float*)d_in[7];
    const float* ad2w  = (const float*)d_in[8];
    const float* b2    = (const float*)d_in[9];
    float* out = (float*)d_out;

    // ws layout (4-byte elems, ~36 MB; 40.4 MB proven available):
    //   row_start[N+4] | csr_src[ETOT] | g[N*16 bf16, in former float slot] |
    //   asb[N] | adb[N] | cvec[64] | pairs[ETOT] | H[M2] | off[M2] |
    //   bsum2[1024] | boff2[1024]
    int* row_start = (int*)d_ws;
    int* csr_src   = row_start + (NNODES + 4);
    float* gslot   = (float*)(csr_src + ETOT);   // N*16 floats reserved
    unsigned short* gbuf = (unsigned short*)gslot;  // N*16 bf16 used
    float* asb     = gslot + (size_t)NNODES * 16;
    float* adb     = asb + NNODES;
    float* cvec    = adb + NNODES;               // 36 floats used
    int* pairs     = (int*)(cvec + 64);          // ETOT
    int* H         = pairs + ETOT;               // M2
    int* off       = H + M2;                     // M2
    int* bsum2     = off + M2;                   // 1024
    int* boff2     = bsum2 + 1024;               // 1024

    const int B = 256;
    const int NB = (NNODES + B - 1) / B;

    // ---- CSR build: deterministic chunked bucket sort ----
    // 1024-thread blocks for the two 256-block kernels (occupancy 9% -> ~37%).
    chunk_hist<<<NCHUNK, 1024, 0, stream>>>(ei, H);
    cscan_local<<<NSB2, 512, 0, stream>>>(H, off, bsum2);
    cscan_bsum<<<1, 1024, 0, stream>>>(bsum2, boff2);
    cscan_add<<<NSB2, 512, 0, stream>>>(off, boff2);
    chunk_scatter<<<NCHUNK, 1024, 0, stream>>>(ei, off, pairs);
    fine_sort2<<<NBUCK, B, 0, stream>>>(off, pairs, row_start, csr_src);

    // ---- attention precompute ----
    prep<<<1, 64, 0, stream>>>(W1, as1w, ad1w, W2, as2w, ad2w, cvec);

    // ---- Layer 1: alphas from x, aggregate x, W1 in epilogue (g stored bf16) ----
    alpha1<<<NB, B, 0, stream>>>(x, cvec, asb, adb);
    agg_l1<<<NNODES / 4, B, 0, stream>>>(row_start, csr_src, asb, adb, x, W1, b1, gbuf);

    // ---- Layer 2: alphas from bf16 g, aggregate bf16 g, W2 in epilogue ----
    alpha2<<<NB, B, 0, stream>>>(gbuf, cvec, asb, adb);
    agg_l2<<<NNODES / 4, B, 0, stream>>>(row_start, csr_src, asb, adb, gbuf, W2, b2, out);
}